// Round 9
// baseline (922.369 us; speedup 1.0000x reference)
//
#include <hip/hip_runtime.h>
#include <math.h>

typedef unsigned short u16;
typedef unsigned int u32;
typedef short bf16x8 __attribute__((ext_vector_type(8)));
typedef float f32x4 __attribute__((ext_vector_type(4)));

#define MFMA16(a, b, c) __builtin_amdgcn_mfma_f32_16x16x32_bf16(a, b, c, 0, 0, 0)

static __device__ __forceinline__ u16 f2b(float f) {
  u32 u = __builtin_bit_cast(u32, f);
  u = (u + 0x7fffu + ((u >> 16) & 1u)) >> 16;
  return (u16)u;
}
static __device__ __forceinline__ float b2f(u16 h) {
  return __builtin_bit_cast(float, ((u32)h) << 16);
}
static __device__ __forceinline__ void gload16(const void* g, void* l) {
  __builtin_amdgcn_global_load_lds((const __attribute__((address_space(1))) void*)g,
                                   (__attribute__((address_space(3))) void*)l, 16, 0, 0);
}
// split f32 into hi-bf16 + lo-bf16 (x ~= hi + lo, rel err ~2^-18)
static __device__ __forceinline__ void split2(float x, u16& hi, u16& lo) {
  hi = f2b(x);
  lo = f2b(x - b2f(hi));
}
static __device__ __forceinline__ float quant1(float x, float scale, float rs) {
  float y = fabsf(x) * rs;
  float st = y < 2.f ? 0.5f : (y < 4.f ? 1.f : 2.f);
  float iv = y < 2.f ? 2.f : (y < 4.f ? 1.f : 0.5f);
  float q = fminf(rintf(y * iv) * st, 6.f);  // rintf = RNE = jnp.round
  return copysignf(q * scale, x);
}

// ---------------- f32 -> bf16 convert ----------------
__global__ __launch_bounds__(256) void k_cvt(const float* __restrict__ in, u16* __restrict__ out) {
  int i = blockIdx.x * 256 + threadIdx.x;
  float4 v = ((const float4*)in)[i];
  u32 lo = (u32)f2b(v.x) | ((u32)f2b(v.y) << 16);
  u32 hi = (u32)f2b(v.z) | ((u32)f2b(v.w) << 16);
  ((uint2*)out)[i] = make_uint2(lo, hi);
}

// ---------------- f32 -> (hi,lo) bf16 split ----------------
__global__ __launch_bounds__(256) void k_splt(const float* __restrict__ in,
                                              u16* __restrict__ hi, u16* __restrict__ lo) {
  int i = blockIdx.x * 256 + threadIdx.x;
  float4 v = ((const float4*)in)[i];
  u16 h[4], l[4];
  split2(v.x, h[0], l[0]);
  split2(v.y, h[1], l[1]);
  split2(v.z, h[2], l[2]);
  split2(v.w, h[3], l[3]);
  ((uint2*)hi)[i] = make_uint2((u32)h[0] | ((u32)h[1] << 16), (u32)h[2] | ((u32)h[3] << 16));
  ((uint2*)lo)[i] = make_uint2((u32)l[0] | ((u32)l[1] << 16), (u32)l[2] | ((u32)l[3] << 16));
}

// ---------------- rope tables: [2048][64] cos & sin ----------------
__global__ __launch_bounds__(256) void k_rope_tab(const int* __restrict__ pid,
                                                  float* __restrict__ ct,
                                                  float* __restrict__ st) {
  int t = blockIdx.x * 256 + threadIdx.x;  // 131072 total
  int s = t >> 6, i = t & 63;
  float inv = powf(10000.f, -(float)i * (1.f / 64.f));
  float a = (float)pid[s] * inv;
  ct[t] = cosf(a);
  st[t] = sinf(a);
}

// ======== 256x256 8-phase bf16 GEMM (T2+T3+T4+T5), both operands gload_lds ========
// C[4096][4096] = A(bf16,[M][K]) * B(bf16,[N][K])^T, BK=64, 8 waves.
// EPI 0/1: rope -> (b,h,s,d) bf16 ; EPI 3: f32 -> d_out.
template <int EPI>
__global__ __launch_bounds__(512, 2) void k_gemm8(const u16* __restrict__ A,
                                                  const u16* __restrict__ B,
                                                  void* __restrict__ outp,
                                                  const float* __restrict__ cost,
                                                  const float* __restrict__ sint) {
  __shared__ u16 Ls[2][2][2][8192];  // [buf][A=0/B=1][half][128*64], 16KB each, 128KB total
  const int tid = threadIdx.x;
  const int wid = tid >> 6, lane = tid & 63;
  const int l15 = lane & 15, lhi = lane >> 4;
  const int wm = wid >> 2, wn = wid & 3;
  const int hib = wn >> 1, sub = wn & 1;

  const int bid = blockIdx.x;
  const int bx = 2 * (bid & 7) + (bid >> 7);   // N-block 0..15
  const int by = (bid >> 3) & 15;              // M-block 0..15
  const int mbase = by * 256, nbase = bx * 256;

  f32x4 acc[8][4];
#pragma unroll
  for (int mi = 0; mi < 8; ++mi)
#pragma unroll
    for (int nj = 0; nj < 4; ++nj) acc[mi][nj] = (f32x4){0.f, 0.f, 0.f, 0.f};

  auto stA = [&](int buf, int half, int ktile) {
    u16* dst = Ls[buf][0][half];
    const int k0 = ktile * 64;
#pragma unroll
    for (int i = 0; i < 2; ++i) {
      int idx = i * 512 + tid;
      int row = idx >> 3;
      int col = k0 + ((((idx & 7) << 4) ^ ((row & 7) << 4)) >> 1);
      gload16(A + (size_t)(mbase + half * 128 + row) * 4096 + col, (char*)dst + idx * 16);
    }
  };
  auto stB = [&](int buf, int half, int ktile) {
    u16* dst = Ls[buf][1][half];
    const int k0 = ktile * 64;
#pragma unroll
    for (int i = 0; i < 2; ++i) {
      int idx = i * 512 + tid;
      int row = idx >> 3;
      int col = k0 + ((((idx & 7) << 4) ^ ((row & 7) << 4)) >> 1);
      gload16(B + (size_t)(nbase + half * 128 + row) * 4096 + col, (char*)dst + idx * 16);
    }
  };

  stB(0, 0, 0);
  stB(0, 1, 0);
  stA(0, 0, 0);
  stA(0, 1, 0);
  stB(1, 0, 1);
  stB(1, 1, 1);

  const int NT = 64;
  for (int kt = 0; kt < NT; ++kt) {
    const int cur = kt & 1, nxt = cur ^ 1;
    const u16* Ab = Ls[cur][0][wm];
    const u16* Bb = Ls[cur][1][hib];
    bf16x8 aA[4][2], aB[4][2], bA[2][2], bB[2][2];

    // ---- phase 0 ----
    if (kt + 1 < NT) stA(nxt, 0, kt + 1);
    if (kt == NT - 1) {
      asm volatile("s_waitcnt vmcnt(0)" ::: "memory");
    } else {
      asm volatile("s_waitcnt vmcnt(6)" ::: "memory");
    }
    __builtin_amdgcn_s_barrier();
#pragma unroll
    for (int mi = 0; mi < 4; ++mi)
#pragma unroll
      for (int ks = 0; ks < 2; ++ks) {
        int row = mi * 16 + l15;
        int kk2 = (ks * 32 + lhi * 8) * 2;
        aA[mi][ks] = *(const bf16x8*)((const char*)Ab + row * 128 + (kk2 ^ ((row & 7) << 4)));
      }
#pragma unroll
    for (int nj = 0; nj < 2; ++nj)
#pragma unroll
      for (int ks = 0; ks < 2; ++ks) {
        int row = sub * 32 + nj * 16 + l15;
        int kk2 = (ks * 32 + lhi * 8) * 2;
        bA[nj][ks] = *(const bf16x8*)((const char*)Bb + row * 128 + (kk2 ^ ((row & 7) << 4)));
      }
    __builtin_amdgcn_s_setprio(1);
#pragma unroll
    for (int mi = 0; mi < 4; ++mi)
#pragma unroll
      for (int nj = 0; nj < 2; ++nj)
#pragma unroll
        for (int ks = 0; ks < 2; ++ks) acc[mi][nj] = MFMA16(aA[mi][ks], bA[nj][ks], acc[mi][nj]);
    __builtin_amdgcn_s_setprio(0);
    __builtin_amdgcn_s_barrier();

    // ---- phase 1 ----
#pragma unroll
    for (int nj = 0; nj < 2; ++nj)
#pragma unroll
      for (int ks = 0; ks < 2; ++ks) {
        int row = 64 + sub * 32 + nj * 16 + l15;
        int kk2 = (ks * 32 + lhi * 8) * 2;
        bB[nj][ks] = *(const bf16x8*)((const char*)Bb + row * 128 + (kk2 ^ ((row & 7) << 4)));
      }
    if (kt + 1 < NT) stA(nxt, 1, kt + 1);
    __builtin_amdgcn_s_barrier();
    __builtin_amdgcn_s_setprio(1);
#pragma unroll
    for (int mi = 0; mi < 4; ++mi)
#pragma unroll
      for (int nj = 0; nj < 2; ++nj)
#pragma unroll
        for (int ks = 0; ks < 2; ++ks)
          acc[mi][nj + 2] = MFMA16(aA[mi][ks], bB[nj][ks], acc[mi][nj + 2]);
    __builtin_amdgcn_s_setprio(0);
    __builtin_amdgcn_s_barrier();

    // ---- phase 2 ----
#pragma unroll
    for (int mi = 0; mi < 4; ++mi)
#pragma unroll
      for (int ks = 0; ks < 2; ++ks) {
        int row = 64 + mi * 16 + l15;
        int kk2 = (ks * 32 + lhi * 8) * 2;
        aB[mi][ks] = *(const bf16x8*)((const char*)Ab + row * 128 + (kk2 ^ ((row & 7) << 4)));
      }
    if (kt + 2 < NT) stB(cur, 0, kt + 2);
    __builtin_amdgcn_s_barrier();
    __builtin_amdgcn_s_setprio(1);
#pragma unroll
    for (int mi = 0; mi < 4; ++mi)
#pragma unroll
      for (int nj = 0; nj < 2; ++nj)
#pragma unroll
        for (int ks = 0; ks < 2; ++ks)
          acc[mi + 4][nj] = MFMA16(aB[mi][ks], bA[nj][ks], acc[mi + 4][nj]);
    __builtin_amdgcn_s_setprio(0);
    __builtin_amdgcn_s_barrier();

    // ---- phase 3 ----
    if (kt + 2 < NT) stB(cur, 1, kt + 2);
    __builtin_amdgcn_s_barrier();
    __builtin_amdgcn_s_setprio(1);
#pragma unroll
    for (int mi = 0; mi < 4; ++mi)
#pragma unroll
      for (int nj = 0; nj < 2; ++nj)
#pragma unroll
        for (int ks = 0; ks < 2; ++ks)
          acc[mi + 4][nj + 2] = MFMA16(aB[mi][ks], bB[nj][ks], acc[mi + 4][nj + 2]);
    __builtin_amdgcn_s_setprio(0);
    __builtin_amdgcn_s_barrier();
  }

  if constexpr (EPI == 3) {
    float* out = (float*)outp;
#pragma unroll
    for (int mi = 0; mi < 8; ++mi)
#pragma unroll
      for (int r = 0; r < 4; ++r) {
        size_t m = (size_t)(mbase + wm * 128 + mi * 16 + lhi * 4 + r);
#pragma unroll
        for (int nj = 0; nj < 4; ++nj) {
          int n = nbase + hib * 128 + (nj >> 1) * 64 + sub * 32 + (nj & 1) * 16 + l15;
          out[m * 4096 + n] = acc[mi][nj][r];
        }
      }
  } else {
    u16* qo = (u16*)outp;
    const int hgl = bx * 2 + hib;
#pragma unroll
    for (int mi = 0; mi < 8; ++mi)
#pragma unroll
      for (int r = 0; r < 4; ++r) {
        int m = mbase + wm * 128 + mi * 16 + lhi * 4 + r;
        int b = m >> 11, s = m & 2047;
        const float* ct = cost + (size_t)s * 64;
        const float* st = sint + (size_t)s * 64;
        size_t base = ((size_t)(b * 32 + hgl) * 2048 + s) * 128;
#pragma unroll
        for (int nj = 0; nj < 2; ++nj) {
          int d = sub * 32 + nj * 16 + l15;
          float c = ct[d], sn = st[d];
          float x1 = acc[mi][nj][r], x2 = acc[mi][nj + 2][r];
          qo[base + d] = f2b(x1 * c - x2 * sn);
          qo[base + d + 64] = f2b(x2 * c + x1 * sn);
        }
      }
  }
}

// ======== V GEMM, 256² tile / BK=32 / 4-phase quadrant schedule (gemm8 clone),
// split-bf16 (Ahi,Alo,Bhi,Blo staged), fused MXFP4 quant. 8 waves, 128KB LDS.
__global__ __launch_bounds__(512, 2) void k_gemmv4(const u16* __restrict__ ahi,
                                                   const u16* __restrict__ alo,
                                                   const u16* __restrict__ bhi,
                                                   const u16* __restrict__ blo,
                                                   u16* __restrict__ vt) {
  __shared__ u16 Ls[2][4][256 * 32];  // [buf][Ahi,Alo,Bhi,Blo][256 rows][32 k], 16KB each
  const int tid = threadIdx.x;
  const int wid = tid >> 6, lane = tid & 63;
  const int l15 = lane & 15, lhi = lane >> 4;
  const int wm = wid >> 2, wn = wid & 3;  // wm: 128-row half (quant block), wn: 64-col quarter
  const int bid = blockIdx.x;
  const int bx = 2 * (bid & 7) + (bid >> 7);
  const int by = (bid >> 3) & 15;
  const int mbase = by * 256, nbase = bx * 256;

  f32x4 acc[8][4];
#pragma unroll
  for (int mi = 0; mi < 8; ++mi)
#pragma unroll
    for (int nj = 0; nj < 4; ++nj) acc[mi][nj] = (f32x4){0.f, 0.f, 0.f, 0.f};

  auto stg = [&](int buf, int mat, int ktile, const u16* src, int rbase) {
    const int k0 = ktile * 32;
#pragma unroll
    for (int i = 0; i < 2; ++i) {
      int idx = i * 512 + tid;  // 0..1023 16B chunks
      int row = idx >> 2, slot = idx & 3;
      int sslot = slot ^ ((row >> 1) & 3);
      gload16(src + (size_t)(rbase + row) * 4096 + k0 + sslot * 8,
              (char*)Ls[buf][mat] + idx * 16);
    }
  };
  auto rd = [&](const u16* base, int row) -> bf16x8 {
    return *(const bf16x8*)((const char*)base + row * 64 + ((lhi ^ ((row >> 1) & 3)) << 4));
  };

  stg(0, 0, 0, ahi, mbase);
  stg(0, 1, 0, alo, mbase);
  stg(0, 2, 0, bhi, nbase);
  stg(0, 3, 0, blo, nbase);
  stg(1, 2, 1, bhi, nbase);
  stg(1, 3, 1, blo, nbase);

  const int NT = 128;
  for (int kt = 0; kt < NT; ++kt) {
    const int cur = kt & 1, nxt = cur ^ 1;
    const u16* AH = Ls[cur][0];
    const u16* AL = Ls[cur][1];
    const u16* BH = Ls[cur][2];
    const u16* BL = Ls[cur][3];
    bf16x8 axh[4], axl[4], ayh[4], ayl[4], bxh[2], bxl[2], byh[2], byl[2];

    // ---- phase 0 ----
    if (kt + 1 < NT) stg(nxt, 0, kt + 1, ahi, mbase);
    if (kt == NT - 1) {
      asm volatile("s_waitcnt vmcnt(0)" ::: "memory");
    } else {
      asm volatile("s_waitcnt vmcnt(6)" ::: "memory");
    }
    __builtin_amdgcn_s_barrier();
#pragma unroll
    for (int mi = 0; mi < 4; ++mi) {
      int row = wm * 128 + mi * 16 + l15;
      axh[mi] = rd(AH, row);
      axl[mi] = rd(AL, row);
    }
#pragma unroll
    for (int nj = 0; nj < 2; ++nj) {
      int row = wn * 64 + nj * 16 + l15;
      bxh[nj] = rd(BH, row);
      bxl[nj] = rd(BL, row);
    }
    __builtin_amdgcn_s_setprio(1);
#pragma unroll
    for (int mi = 0; mi < 4; ++mi)
#pragma unroll
      for (int nj = 0; nj < 2; ++nj) {
        acc[mi][nj] = MFMA16(axh[mi], bxh[nj], acc[mi][nj]);
        acc[mi][nj] = MFMA16(axh[mi], bxl[nj], acc[mi][nj]);
        acc[mi][nj] = MFMA16(axl[mi], bxh[nj], acc[mi][nj]);
      }
    __builtin_amdgcn_s_setprio(0);
    __builtin_amdgcn_s_barrier();

    // ---- phase 1 ----
#pragma unroll
    for (int nj = 0; nj < 2; ++nj) {
      int row = wn * 64 + 32 + nj * 16 + l15;
      byh[nj] = rd(BH, row);
      byl[nj] = rd(BL, row);
    }
    if (kt + 1 < NT) stg(nxt, 1, kt + 1, alo, mbase);
    __builtin_amdgcn_s_barrier();
    __builtin_amdgcn_s_setprio(1);
#pragma unroll
    for (int mi = 0; mi < 4; ++mi)
#pragma unroll
      for (int nj = 0; nj < 2; ++nj) {
        acc[mi][nj + 2] = MFMA16(axh[mi], byh[nj], acc[mi][nj + 2]);
        acc[mi][nj + 2] = MFMA16(axh[mi], byl[nj], acc[mi][nj + 2]);
        acc[mi][nj + 2] = MFMA16(axl[mi], byh[nj], acc[mi][nj + 2]);
      }
    __builtin_amdgcn_s_setprio(0);
    __builtin_amdgcn_s_barrier();

    // ---- phase 2 ----
#pragma unroll
    for (int mi = 0; mi < 4; ++mi) {
      int row = wm * 128 + 64 + mi * 16 + l15;
      ayh[mi] = rd(AH, row);
      ayl[mi] = rd(AL, row);
    }
    if (kt + 2 < NT) stg(cur, 2, kt + 2, bhi, nbase);
    __builtin_amdgcn_s_barrier();
    __builtin_amdgcn_s_setprio(1);
#pragma unroll
    for (int mi = 0; mi < 4; ++mi)
#pragma unroll
      for (int nj = 0; nj < 2; ++nj) {
        acc[mi + 4][nj] = MFMA16(ayh[mi], bxh[nj], acc[mi + 4][nj]);
        acc[mi + 4][nj] = MFMA16(ayh[mi], bxl[nj], acc[mi + 4][nj]);
        acc[mi + 4][nj] = MFMA16(ayl[mi], bxh[nj], acc[mi + 4][nj]);
      }
    __builtin_amdgcn_s_setprio(0);
    __builtin_amdgcn_s_barrier();

    // ---- phase 3 ----
    if (kt + 2 < NT) stg(cur, 3, kt + 2, blo, nbase);
    __builtin_amdgcn_s_barrier();
    __builtin_amdgcn_s_setprio(1);
#pragma unroll
    for (int mi = 0; mi < 4; ++mi)
#pragma unroll
      for (int nj = 0; nj < 2; ++nj) {
        acc[mi + 4][nj + 2] = MFMA16(ayh[mi], byh[nj], acc[mi + 4][nj + 2]);
        acc[mi + 4][nj + 2] = MFMA16(ayh[mi], byl[nj], acc[mi + 4][nj + 2]);
        acc[mi + 4][nj + 2] = MFMA16(ayl[mi], byh[nj], acc[mi + 4][nj + 2]);
      }
    __builtin_amdgcn_s_setprio(0);
    __builtin_amdgcn_s_barrier();
  }

  // ---- fused MXFP4 quant: wave's 128 rows == exactly one quant block -> wave-local amax ----
  const int h = (nbase >> 7) + (wn >> 1);
  const int d0 = (wn & 1) * 64;
#pragma unroll
  for (int nj = 0; nj < 4; ++nj) {
    float a = 0.f;
#pragma unroll
    for (int mi = 0; mi < 8; ++mi)
#pragma unroll
      for (int r = 0; r < 4; ++r) a = fmaxf(a, fabsf(acc[mi][nj][r]));
    a = fmaxf(a, __shfl_xor(a, 16));
    a = fmaxf(a, __shfl_xor(a, 32));
    float scale = 1.f, rs = 1.f;
    if (a > 0.f) {
      int e;
      float mant = frexpf(a, &e);
      int cc = (mant == 0.5f) ? (e - 1) : e;  // exact ceil(log2(amax))
      scale = ldexpf(1.f, cc - 3);
      rs = ldexpf(1.f, 3 - cc);
    }
    int d = d0 + nj * 16 + l15;
#pragma unroll
    for (int mi = 0; mi < 8; ++mi) {
      int m0 = mbase + wm * 128 + mi * 16 + lhi * 4;
      int b = m0 >> 11, s0 = m0 & 2047;
      uint2 pk;
      float v0 = quant1(acc[mi][nj][0], scale, rs);
      float v1 = quant1(acc[mi][nj][1], scale, rs);
      float v2 = quant1(acc[mi][nj][2], scale, rs);
      float v3 = quant1(acc[mi][nj][3], scale, rs);
      pk.x = (u32)f2b(v0) | ((u32)f2b(v1) << 16);
      pk.y = (u32)f2b(v2) | ((u32)f2b(v3) << 16);
      *(uint2*)(vt + ((size_t)(b * 32 + h) * 128 + d) * 2048 + s0) = pk;
    }
  }
}

// ======== FALLBACK PATH (used when ws_size is small) ========
template <int EPI>
__global__ __launch_bounds__(256) void k_gemm(const u16* __restrict__ A,
                                              const float* __restrict__ B,
                                              void* __restrict__ outp,
                                              const float* __restrict__ cost,
                                              const float* __restrict__ sint) {
  __shared__ u16 As[128 * 64];
  __shared__ u16 Bs[128 * 64];
  const int tid = threadIdx.x;
  const int w = tid >> 6, lane = tid & 63;
  const int l15 = lane & 15, lhi = lane >> 4;
  const int mbase = blockIdx.y * 128, nbase = blockIdx.x * 128;
  f32x4 acc[2][8];
#pragma unroll
  for (int i = 0; i < 2; ++i)
#pragma unroll
    for (int j = 0; j < 8; ++j) acc[i][j] = (f32x4){0.f, 0.f, 0.f, 0.f};

  const int brow = tid >> 1, bk = (tid & 1) * 32;
  const float* bsrc = B + (size_t)(nbase + brow) * 4096 + bk;

  for (int kt = 0; kt < 64; ++kt) {
    const int k0 = kt * 64;
#pragma unroll
    for (int i = 0; i < 4; ++i) {
      int idx = i * 256 + tid;
      int row = idx >> 3;
      int inb = ((idx & 7) << 4) ^ ((row & 7) << 4);
      gload16(A + (size_t)(mbase + row) * 4096 + (k0 + (inb >> 1)), (char*)As + idx * 16);
    }
    float4 bv[8];
    const float* bp = bsrc + k0;
#pragma unroll
    for (int c = 0; c < 8; ++c) bv[c] = *(const float4*)(bp + c * 4);
#pragma unroll
    for (int c = 0; c < 4; ++c) {
      uint4 pk;
      pk.x = (u32)f2b(bv[2 * c].x) | ((u32)f2b(bv[2 * c].y) << 16);
      pk.y = (u32)f2b(bv[2 * c].z) | ((u32)f2b(bv[2 * c].w) << 16);
      pk.z = (u32)f2b(bv[2 * c + 1].x) | ((u32)f2b(bv[2 * c + 1].y) << 16);
      pk.w = (u32)f2b(bv[2 * c + 1].z) | ((u32)f2b(bv[2 * c + 1].w) << 16);
      int byte = brow * 128 + (((bk + c * 8) * 2) ^ ((brow & 7) << 4));
      *(uint4*)((char*)Bs + byte) = pk;
    }
    __syncthreads();
#pragma unroll
    for (int ks = 0; ks < 2; ++ks) {
      const int kk2 = (ks * 32 + lhi * 8) * 2;
      bf16x8 af[2], bfr[8];
#pragma unroll
      for (int i = 0; i < 2; ++i) {
        int row = w * 32 + i * 16 + l15;
        af[i] = *(const bf16x8*)((const char*)As + row * 128 + (kk2 ^ ((row & 7) << 4)));
      }
#pragma unroll
      for (int j = 0; j < 8; ++j) {
        int row = j * 16 + l15;
        bfr[j] = *(const bf16x8*)((const char*)Bs + row * 128 + (kk2 ^ ((row & 7) << 4)));
      }
#pragma unroll
      for (int i = 0; i < 2; ++i)
#pragma unroll
        for (int j = 0; j < 8; ++j) acc[i][j] = MFMA16(af[i], bfr[j], acc[i][j]);
    }
    __syncthreads();
  }

  const int h = nbase >> 7;
  if constexpr (EPI == 3) {
    float* out = (float*)outp;
#pragma unroll
    for (int i = 0; i < 2; ++i)
#pragma unroll
      for (int r = 0; r < 4; ++r) {
        size_t m = (size_t)(mbase + w * 32 + i * 16 + lhi * 4 + r);
#pragma unroll
        for (int j = 0; j < 8; ++j) out[m * 4096 + nbase + j * 16 + l15] = acc[i][j][r];
      }
  } else {
    u16* qo = (u16*)outp;
#pragma unroll
    for (int i = 0; i < 2; ++i)
#pragma unroll
      for (int r = 0; r < 4; ++r) {
        int m = mbase + w * 32 + i * 16 + lhi * 4 + r;
        int b = m >> 11, s = m & 2047;
        const float* ct = cost + (size_t)s * 64;
        const float* st = sint + (size_t)s * 64;
        size_t base = ((size_t)(b * 32 + h) * 2048 + s) * 128;
#pragma unroll
        for (int j = 0; j < 4; ++j) {
          int d = j * 16 + l15;
          float c = ct[d], sn = st[d];
          float x1 = acc[i][j][r], x2 = acc[i][j + 4][r];
          qo[base + d] = f2b(x1 * c - x2 * sn);
          qo[base + d + 64] = f2b(x2 * c + x1 * sn);
        }
      }
  }
}

__global__ __launch_bounds__(256) void k_gemmv(const float* __restrict__ hsf,
                                               const float* __restrict__ Wv,
                                               u16* __restrict__ vt) {
  __shared__ u16 AsHi[128 * 64];
  __shared__ u16 AsLo[128 * 64];
  __shared__ u16 BsHi[128 * 64];
  __shared__ u16 BsLo[128 * 64];
  const int tid = threadIdx.x;
  const int w = tid >> 6, lane = tid & 63;
  const int l15 = lane & 15, lhi = lane >> 4;
  const int mbase = blockIdx.y * 128, nbase = blockIdx.x * 128;
  f32x4 acc[2][8];
#pragma unroll
  for (int i = 0; i < 2; ++i)
#pragma unroll
    for (int j = 0; j < 8; ++j) acc[i][j] = (f32x4){0.f, 0.f, 0.f, 0.f};

  const int srow = tid >> 1, sk = (tid & 1) * 32;
  const float* asrc = hsf + (size_t)(mbase + srow) * 4096 + sk;
  const float* bsrc = Wv + (size_t)(nbase + srow) * 4096 + sk;

  for (int kt = 0; kt < 64; ++kt) {
    const int k0 = kt * 64;
    float4 av[8], bv[8];
#pragma unroll
    for (int c = 0; c < 8; ++c) {
      av[c] = *(const float4*)(asrc + k0 + c * 4);
      bv[c] = *(const float4*)(bsrc + k0 + c * 4);
    }
#pragma unroll
    for (int c = 0; c < 4; ++c) {
      u16 h0, l0, h1, l1;
      float fa[8] = {av[2 * c].x, av[2 * c].y, av[2 * c].z, av[2 * c].w,
                     av[2 * c + 1].x, av[2 * c + 1].y, av[2 * c + 1].z, av[2 * c + 1].w};
      float fb[8] = {bv[2 * c].x, bv[2 * c].y, bv[2 * c].z, bv[2 * c].w,
                     bv[2 * c + 1].x, bv[2 * c + 1].y, bv[2 * c + 1].z, bv[2 * c + 1].w};
      u32 ph[4], pl[4], qh[4], ql[4];
#pragma unroll
      for (int t = 0; t < 4; ++t) {
        split2(fa[2 * t], h0, l0);
        split2(fa[2 * t + 1], h1, l1);
        ph[t] = (u32)h0 | ((u32)h1 << 16);
        pl[t] = (u32)l0 | ((u32)l1 << 16);
        split2(fb[2 * t], h0, l0);
        split2(fb[2 * t + 1], h1, l1);
        qh[t] = (u32)h0 | ((u32)h1 << 16);
        ql[t] = (u32)l0 | ((u32)l1 << 16);
      }
      int byte = srow * 128 + (((sk + c * 8) * 2) ^ ((srow & 7) << 4));
      *(uint4*)((char*)AsHi + byte) = make_uint4(ph[0], ph[1], ph[2], ph[3]);
      *(uint4*)((char*)AsLo + byte) = make_uint4(pl[0], pl[1], pl[2], pl[3]);
      *(uint4*)((char*)BsHi + byte) = make_uint4(qh[0], qh[1], qh[2], qh[3]);
      *(uint4*)((char*)BsLo + byte) = make_uint4(ql[0], ql[1], ql[2], ql[3]);
    }
    __syncthreads();
#pragma unroll
    for (int ks = 0; ks < 2; ++ks) {
      const int kk2 = (ks * 32 + lhi * 8) * 2;
      bf16x8 afh[2], afl[2];
#pragma unroll
      for (int i = 0; i < 2; ++i) {
        int row = w * 32 + i * 16 + l15;
        int off = row * 128 + (kk2 ^ ((row & 7) << 4));
        afh[i] = *(const bf16x8*)((const char*)AsHi + off);
        afl[i] = *(const bf16x8*)((const char*)AsLo + off);
      }
#pragma unroll
      for (int j = 0; j < 8; ++j) {
        int row = j * 16 + l15;
        int off = row * 128 + (kk2 ^ ((row & 7) << 4));
        bf16x8 bh = *(const bf16x8*)((const char*)BsHi + off);
        bf16x8 bl = *(const bf16x8*)((const char*)BsLo + off);
#pragma unroll
        for (int i = 0; i < 2; ++i) {
          acc[i][j] = MFMA16(afh[i], bh, acc[i][j]);
          acc[i][j] = MFMA16(afh[i], bl, acc[i][j]);
          acc[i][j] = MFMA16(afl[i], bh, acc[i][j]);
        }
      }
    }
    __syncthreads();
  }

  const int h = nbase >> 7;
  float pam[8];
#pragma unroll
  for (int j = 0; j < 8; ++j) {
    float a = 0.f;
#pragma unroll
    for (int i = 0; i < 2; ++i)
#pragma unroll
      for (int r = 0; r < 4; ++r) a = fmaxf(a, fabsf(acc[i][j][r]));
    a = fmaxf(a, __shfl_xor(a, 16));
    a = fmaxf(a, __shfl_xor(a, 32));
    pam[j] = a;
  }
  float* red = (float*)BsHi;
  if (lhi == 0) {
#pragma unroll
    for (int j = 0; j < 8; ++j) red[w * 128 + j * 16 + l15] = pam[j];
  }
  __syncthreads();
#pragma unroll
  for (int j = 0; j < 8; ++j) {
    float amax = fmaxf(fmaxf(red[0 * 128 + j * 16 + l15], red[1 * 128 + j * 16 + l15]),
                       fmaxf(red[2 * 128 + j * 16 + l15], red[3 * 128 + j * 16 + l15]));
    float scale = 1.f, rs = 1.f;
    if (amax > 0.f) {
      int e;
      float mant = frexpf(amax, &e);
      int c = (mant == 0.5f) ? (e - 1) : e;
      scale = ldexpf(1.f, c - 3);
      rs = ldexpf(1.f, 3 - c);
    }
#pragma unroll
    for (int i = 0; i < 2; ++i) {
      int m0 = mbase + w * 32 + i * 16 + lhi * 4;
      int b = m0 >> 11, s0 = m0 & 2047;
      int d = j * 16 + l15;
      uint2 pk;
      float v0 = quant1(acc[i][j][0], scale, rs);
      float v1 = quant1(acc[i][j][1], scale, rs);
      float v2 = quant1(acc[i][j][2], scale, rs);
      float v3 = quant1(acc[i][j][3], scale, rs);
      pk.x = (u32)f2b(v0) | ((u32)f2b(v1) << 16);
      pk.y = (u32)f2b(v2) | ((u32)f2b(v3) << 16);
      *(uint2*)(vt + ((size_t)(b * 32 + h) * 128 + d) * 2048 + s0) = pk;
    }
  }
}

// ---------------- R9 flash attention (causal): QB=64 (4 waves), KB=32, 4 blocks/CU ----------------
// LDS 37.9KB -> 4 blocks/CU = 16 waves/CU (2x R8's TLP); dbuf K/V + counted vmcnt(4).
__global__ __launch_bounds__(256, 4) void k_attn(const u16* __restrict__ qg,
                                                 const u16* __restrict__ kg,
                                                 const u16* __restrict__ vtg,
                                                 u16* __restrict__ ao) {
  __shared__ u16 Ks[2][32 * 128];  // [kk][d], 256B rows, swizzled by ((row&15)<<4)
  __shared__ u16 Vs[2][128 * 32];  // [d][s], 64B rows, swizzled by ((row&3)<<4)
  __shared__ u16 Ps[4 * 16 * 40];  // per-wave P, row stride 80B (16B-aligned, 20-bank step)
  const int qt = 31 - blockIdx.y;  // longest blocks dispatch first
  const int bh = blockIdx.x;
  const int tid = threadIdx.x, w = tid >> 6, lane = tid & 63;
  const int l15 = lane & 15, lhi = lane >> 4;
  const size_t bhoff = (size_t)bh * (2048 * 128);
  const float SC = 0.08838834764831845f;  // 1/sqrt(128)

  bf16x8 qf[4];
  {
    const int qrow = qt * 64 + w * 16 + l15;
    const u16* qp = qg + bhoff + (size_t)qrow * 128 + lhi * 8;
#pragma unroll
    for (int ks = 0; ks < 4; ++ks) qf[ks] = *(const bf16x8*)(qp + ks * 32);
  }
  f32x4 oacc[8];
#pragma unroll
  for (int dt = 0; dt < 8; ++dt) oacc[dt] = (f32x4){0.f, 0.f, 0.f, 0.f};
  float mrow[4] = {-1e30f, -1e30f, -1e30f, -1e30f};
  float lrow[4] = {0.f, 0.f, 0.f, 0.f};

  // stage one K/V tile: 2 K-chunks + 2 V-chunks per thread (4 gload_lds)
  auto stage = [&](int buf, int kbase) {
#pragma unroll
    for (int i = 0; i < 2; ++i) {
      int idx = i * 256 + tid;   // 512 chunks, 16 per 256B K-row
      int row = idx >> 4;
      int inb = ((idx & 15) << 4) ^ ((row & 15) << 4);
      gload16(kg + bhoff + (size_t)(kbase + row) * 128 + (inb >> 1), (char*)Ks[buf] + idx * 16);
    }
#pragma unroll
    for (int i = 0; i < 2; ++i) {
      int idx = i * 256 + tid;   // 512 chunks, 4 per 64B V-row
      int row = idx >> 2, slot = idx & 3;
      int ss = slot ^ (row & 3);
      gload16(vtg + bhoff + (size_t)row * 2048 + kbase + ss * 8, (char*)Vs[buf] + idx * 16);
    }
  };

  const int nt = 2 * qt + 2;  // 32-wide tiles up to k = (qt+1)*64
  stage(0, 0);

  for (int kt = 0; kt < nt; ++kt) {
    const int cur = kt & 1;
    if (kt < nt - 1) {
      stage(cur ^ 1, (kt + 1) * 32);
      asm volatile("s_waitcnt vmcnt(4)" ::: "memory");  // wait only the OLD 4
    } else {
      asm volatile("s_waitcnt vmcnt(0)" ::: "memory");
    }
    __builtin_amdgcn_s_barrier();

    // QK^T: 16x32 per wave
    f32x4 sc4[2];
#pragma unroll
    for (int j = 0; j < 2; ++j) sc4[j] = (f32x4){0.f, 0.f, 0.f, 0.f};
#pragma unroll
    for (int ks = 0; ks < 4; ++ks) {
      const int db = (ks * 32 + lhi * 8) * 2;
#pragma unroll
      for (int j = 0; j < 2; ++j) {
        int kr = j * 16 + l15;
        bf16x8 bfr = *(const bf16x8*)((const char*)Ks[cur] + kr * 256 + (db ^ ((kr & 15) << 4)));
        sc4[j] = MFMA16(qf[ks], bfr, sc4[j]);
      }
    }
    float p[2][4];
    const int kb_ = kt * 32;
    const bool tail = (kt >= 2 * qt);
#pragma unroll
    for (int j = 0; j < 2; ++j)
#pragma unroll
      for (int r = 0; r < 4; ++r) {
        float s = sc4[j][r] * SC;
        if (tail && (kb_ + j * 16 + l15 > qt * 64 + w * 16 + lhi * 4 + r)) s = -1e9f;
        p[j][r] = s;
      }
    float alpha[4];
#pragma unroll
    for (int r = 0; r < 4; ++r) {
      float tm = fmaxf(p[0][r], p[1][r]);
      tm = fmaxf(tm, __shfl_xor(tm, 1));
      tm = fmaxf(tm, __shfl_xor(tm, 2));
      tm = fmaxf(tm, __shfl_xor(tm, 4));
      tm = fmaxf(tm, __shfl_xor(tm, 8));
      float mn = fmaxf(mrow[r], tm);
      alpha[r] = __expf(mrow[r] - mn);
      mrow[r] = mn;
      float rsum = 0.f;
#pragma unroll
      for (int j = 0; j < 2; ++j) {
        float e = __expf(p[j][r] - mn);
        p[j][r] = e;
        rsum += e;
      }
      rsum += __shfl_xor(rsum, 1);
      rsum += __shfl_xor(rsum, 2);
      rsum += __shfl_xor(rsum, 4);
      rsum += __shfl_xor(rsum, 8);
      lrow[r] = lrow[r] * alpha[r] + rsum;
    }
#pragma unroll
    for (int dt = 0; dt < 8; ++dt) {
      f32x4 t = oacc[dt];
      t[0] *= alpha[0]; t[1] *= alpha[1]; t[2] *= alpha[2]; t[3] *= alpha[3];
      oacc[dt] = t;
    }
    // P -> per-wave LDS, then PV (one K=32 slab)
#pragma unroll
    for (int j = 0; j < 2; ++j)
#pragma unroll
      for (int r = 0; r < 4; ++r)
        Ps[w * 640 + (lhi * 4 + r) * 40 + j * 16 + l15] = f2b(p[j][r]);
    bf16x8 pa = *(const bf16x8*)((const char*)Ps + w * 1280 + l15 * 80 + lhi * 16);
#pragma unroll
    for (int dt = 0; dt < 8; ++dt) {
      int d = dt * 16 + l15;
      bf16x8 vb = *(const bf16x8*)((const char*)Vs[cur] + d * 64 + ((lhi * 16) ^ ((d & 3) << 4)));
      oacc[dt] = MFMA16(pa, vb, oacc[dt]);
    }
    // all LDS reads of buf[cur] done before next iter's DMA may overwrite it
    asm volatile("s_waitcnt lgkmcnt(0)" ::: "memory");
    __builtin_amdgcn_s_barrier();
  }

  const int b = bh >> 5, h = bh & 31;
  float inv[4];
#pragma unroll
  for (int r = 0; r < 4; ++r) inv[r] = 1.f / lrow[r];
#pragma unroll
  for (int dt = 0; dt < 8; ++dt)
#pragma unroll
    for (int r = 0; r < 4; ++r) {
      int s = qt * 64 + w * 16 + lhi * 4 + r;
      ao[((size_t)(b * 2048 + s)) * 4096 + h * 128 + dt * 16 + l15] = f2b(oacc[dt][r] * inv[r]);
    }
}

extern "C" void kernel_launch(void* const* d_in, const int* in_sizes, int n_in,
                              void* d_out, int out_size, void* d_ws, size_t ws_size,
                              hipStream_t stream) {
  (void)in_sizes; (void)n_in; (void)out_size;
  const float* hs = (const float*)d_in[0];
  const int* pid = (const int*)d_in[1];
  const float* Wq = (const float*)d_in[2];
  const float* Wk = (const float*)d_in[3];
  const float* Wv = (const float*)d_in[4];
  const float* Wo = (const float*)d_in[5];
  float* out = (float*)d_out;
  char* ws = (char*)d_ws;

  const size_t BUF = 33554432;  // one 4096x4096 bf16 buffer
  const size_t NEED = 7 * BUF + 2 * 524288;

  if (ws_size >= NEED) {
    u16* hsb  = (u16*)(ws + 0 * BUF);          // hs hi
    u16* hslo = (u16*)(ws + 1 * BUF);          // hs lo; later aob
    u16* qb   = (u16*)(ws + 2 * BUF);
    u16* kb   = (u16*)(ws + 3 * BUF);
    u16* vtb  = (u16*)(ws + 4 * BUF);
    u16* wbuf = (u16*)(ws + 5 * BUF);          // Wq_b -> Wk_b -> Wv_hi -> Wo_b (sequential)
    u16* wvlo = (u16*)(ws + 6 * BUF);
    float* cost = (float*)(ws + 7 * BUF);
    float* sint = (float*)(ws + 7 * BUF + 524288);
    u16* aob = hslo;

    k_splt<<<16384, 256, 0, stream>>>(hs, hsb, hslo);
    k_rope_tab<<<512, 256, 0, stream>>>(pid, cost, sint);
    k_cvt<<<16384, 256, 0, stream>>>(Wq, wbuf);
    k_gemm8<0><<<256, 512, 0, stream>>>(hsb, wbuf, (void*)qb, cost, sint);
    k_cvt<<<16384, 256, 0, stream>>>(Wk, wbuf);
    k_gemm8<1><<<256, 512, 0, stream>>>(hsb, wbuf, (void*)kb, cost, sint);
    k_splt<<<16384, 256, 0, stream>>>(Wv, wbuf, wvlo);
    k_gemmv4<<<256, 512, 0, stream>>>(hsb, hslo, wbuf, wvlo, vtb);
    k_attn<<<dim3(64, 32), 256, 0, stream>>>(qb, kb, vtb, aob);
    k_cvt<<<16384, 256, 0, stream>>>(Wo, wbuf);
    k_gemm8<3><<<256, 512, 0, stream>>>(aob, wbuf, (void*)out, nullptr, nullptr);
  } else {
    u16* hsb = (u16*)(ws + 0);
    u16* qb  = (u16*)(ws + 33554432);
    u16* kb  = (u16*)(ws + 67108864);
    u16* vtb = (u16*)(ws + 100663296);
    float* cost = (float*)(ws + 134217728);
    float* sint = (float*)(ws + 134742016);
    u16* aob = hsb;

    k_cvt<<<16384, 256, 0, stream>>>(hs, hsb);
    k_rope_tab<<<512, 256, 0, stream>>>(pid, cost, sint);
    k_gemm<0><<<dim3(32, 32), 256, 0, stream>>>(hsb, Wq, (void*)qb, cost, sint);
    k_gemm<1><<<dim3(32, 32), 256, 0, stream>>>(hsb, Wk, (void*)kb, cost, sint);
    k_gemmv<<<dim3(32, 32), 256, 0, stream>>>(hs, Wv, vtb);
    k_attn<<<dim3(64, 32), 256, 0, stream>>>(qb, kb, vtb, aob);
    k_gemm<3><<<dim3(32, 32), 256, 0, stream>>>(aob, Wo, (void*)out, nullptr, nullptr);
  }
}

// Round 10
// 880.335 us; speedup vs baseline: 1.0477x; 1.0477x over previous
//
#include <hip/hip_runtime.h>
#include <math.h>

typedef unsigned short u16;
typedef unsigned int u32;
typedef short bf16x8 __attribute__((ext_vector_type(8)));
typedef float f32x4 __attribute__((ext_vector_type(4)));

#define MFMA16(a, b, c) __builtin_amdgcn_mfma_f32_16x16x32_bf16(a, b, c, 0, 0, 0)

static __device__ __forceinline__ u16 f2b(float f) {
  u32 u = __builtin_bit_cast(u32, f);
  u = (u + 0x7fffu + ((u >> 16) & 1u)) >> 16;
  return (u16)u;
}
static __device__ __forceinline__ float b2f(u16 h) {
  return __builtin_bit_cast(float, ((u32)h) << 16);
}
static __device__ __forceinline__ void gload16(const void* g, void* l) {
  __builtin_amdgcn_global_load_lds((const __attribute__((address_space(1))) void*)g,
                                   (__attribute__((address_space(3))) void*)l, 16, 0, 0);
}
// split f32 into hi-bf16 + lo-bf16 (x ~= hi + lo, rel err ~2^-18)
static __device__ __forceinline__ void split2(float x, u16& hi, u16& lo) {
  hi = f2b(x);
  lo = f2b(x - b2f(hi));
}
static __device__ __forceinline__ float quant1(float x, float scale, float rs) {
  float y = fabsf(x) * rs;
  float st = y < 2.f ? 0.5f : (y < 4.f ? 1.f : 2.f);
  float iv = y < 2.f ? 2.f : (y < 4.f ? 1.f : 0.5f);
  float q = fminf(rintf(y * iv) * st, 6.f);  // rintf = RNE = jnp.round
  return copysignf(q * scale, x);
}

// ---------------- f32 -> bf16 convert ----------------
__global__ __launch_bounds__(256) void k_cvt(const float* __restrict__ in, u16* __restrict__ out) {
  int i = blockIdx.x * 256 + threadIdx.x;
  float4 v = ((const float4*)in)[i];
  u32 lo = (u32)f2b(v.x) | ((u32)f2b(v.y) << 16);
  u32 hi = (u32)f2b(v.z) | ((u32)f2b(v.w) << 16);
  ((uint2*)out)[i] = make_uint2(lo, hi);
}

// ---------------- f32 -> (hi,lo) bf16 split ----------------
__global__ __launch_bounds__(256) void k_splt(const float* __restrict__ in,
                                              u16* __restrict__ hi, u16* __restrict__ lo) {
  int i = blockIdx.x * 256 + threadIdx.x;
  float4 v = ((const float4*)in)[i];
  u16 h[4], l[4];
  split2(v.x, h[0], l[0]);
  split2(v.y, h[1], l[1]);
  split2(v.z, h[2], l[2]);
  split2(v.w, h[3], l[3]);
  ((uint2*)hi)[i] = make_uint2((u32)h[0] | ((u32)h[1] << 16), (u32)h[2] | ((u32)h[3] << 16));
  ((uint2*)lo)[i] = make_uint2((u32)l[0] | ((u32)l[1] << 16), (u32)l[2] | ((u32)l[3] << 16));
}

// ---------------- rope tables: [2048][64] cos & sin ----------------
__global__ __launch_bounds__(256) void k_rope_tab(const int* __restrict__ pid,
                                                  float* __restrict__ ct,
                                                  float* __restrict__ st) {
  int t = blockIdx.x * 256 + threadIdx.x;  // 131072 total
  int s = t >> 6, i = t & 63;
  float inv = powf(10000.f, -(float)i * (1.f / 64.f));
  float a = (float)pid[s] * inv;
  ct[t] = cosf(a);
  st[t] = sinf(a);
}

// ======== 256x256 8-phase bf16 GEMM (T2+T3+T4+T5), both operands gload_lds ========
// C[4096][4096] = A(bf16,[M][K]) * B(bf16,[N][K])^T, BK=64, 8 waves.
// EPI 0/1: rope -> (b,h,s,d) bf16 ; EPI 3: f32 -> d_out.
template <int EPI>
__global__ __launch_bounds__(512, 2) void k_gemm8(const u16* __restrict__ A,
                                                  const u16* __restrict__ B,
                                                  void* __restrict__ outp,
                                                  const float* __restrict__ cost,
                                                  const float* __restrict__ sint) {
  __shared__ u16 Ls[2][2][2][8192];  // [buf][A=0/B=1][half][128*64], 16KB each, 128KB total
  const int tid = threadIdx.x;
  const int wid = tid >> 6, lane = tid & 63;
  const int l15 = lane & 15, lhi = lane >> 4;
  const int wm = wid >> 2, wn = wid & 3;
  const int hib = wn >> 1, sub = wn & 1;

  const int bid = blockIdx.x;
  const int bx = 2 * (bid & 7) + (bid >> 7);   // N-block 0..15
  const int by = (bid >> 3) & 15;              // M-block 0..15
  const int mbase = by * 256, nbase = bx * 256;

  f32x4 acc[8][4];
#pragma unroll
  for (int mi = 0; mi < 8; ++mi)
#pragma unroll
    for (int nj = 0; nj < 4; ++nj) acc[mi][nj] = (f32x4){0.f, 0.f, 0.f, 0.f};

  auto stA = [&](int buf, int half, int ktile) {
    u16* dst = Ls[buf][0][half];
    const int k0 = ktile * 64;
#pragma unroll
    for (int i = 0; i < 2; ++i) {
      int idx = i * 512 + tid;
      int row = idx >> 3;
      int col = k0 + ((((idx & 7) << 4) ^ ((row & 7) << 4)) >> 1);
      gload16(A + (size_t)(mbase + half * 128 + row) * 4096 + col, (char*)dst + idx * 16);
    }
  };
  auto stB = [&](int buf, int half, int ktile) {
    u16* dst = Ls[buf][1][half];
    const int k0 = ktile * 64;
#pragma unroll
    for (int i = 0; i < 2; ++i) {
      int idx = i * 512 + tid;
      int row = idx >> 3;
      int col = k0 + ((((idx & 7) << 4) ^ ((row & 7) << 4)) >> 1);
      gload16(B + (size_t)(nbase + half * 128 + row) * 4096 + col, (char*)dst + idx * 16);
    }
  };

  stB(0, 0, 0);
  stB(0, 1, 0);
  stA(0, 0, 0);
  stA(0, 1, 0);
  stB(1, 0, 1);
  stB(1, 1, 1);

  const int NT = 64;
  for (int kt = 0; kt < NT; ++kt) {
    const int cur = kt & 1, nxt = cur ^ 1;
    const u16* Ab = Ls[cur][0][wm];
    const u16* Bb = Ls[cur][1][hib];
    bf16x8 aA[4][2], aB[4][2], bA[2][2], bB[2][2];

    // ---- phase 0 ----
    if (kt + 1 < NT) stA(nxt, 0, kt + 1);
    if (kt == NT - 1) {
      asm volatile("s_waitcnt vmcnt(0)" ::: "memory");
    } else {
      asm volatile("s_waitcnt vmcnt(6)" ::: "memory");
    }
    __builtin_amdgcn_s_barrier();
#pragma unroll
    for (int mi = 0; mi < 4; ++mi)
#pragma unroll
      for (int ks = 0; ks < 2; ++ks) {
        int row = mi * 16 + l15;
        int kk2 = (ks * 32 + lhi * 8) * 2;
        aA[mi][ks] = *(const bf16x8*)((const char*)Ab + row * 128 + (kk2 ^ ((row & 7) << 4)));
      }
#pragma unroll
    for (int nj = 0; nj < 2; ++nj)
#pragma unroll
      for (int ks = 0; ks < 2; ++ks) {
        int row = sub * 32 + nj * 16 + l15;
        int kk2 = (ks * 32 + lhi * 8) * 2;
        bA[nj][ks] = *(const bf16x8*)((const char*)Bb + row * 128 + (kk2 ^ ((row & 7) << 4)));
      }
    __builtin_amdgcn_s_setprio(1);
#pragma unroll
    for (int mi = 0; mi < 4; ++mi)
#pragma unroll
      for (int nj = 0; nj < 2; ++nj)
#pragma unroll
        for (int ks = 0; ks < 2; ++ks) acc[mi][nj] = MFMA16(aA[mi][ks], bA[nj][ks], acc[mi][nj]);
    __builtin_amdgcn_s_setprio(0);
    __builtin_amdgcn_s_barrier();

    // ---- phase 1 ----
#pragma unroll
    for (int nj = 0; nj < 2; ++nj)
#pragma unroll
      for (int ks = 0; ks < 2; ++ks) {
        int row = 64 + sub * 32 + nj * 16 + l15;
        int kk2 = (ks * 32 + lhi * 8) * 2;
        bB[nj][ks] = *(const bf16x8*)((const char*)Bb + row * 128 + (kk2 ^ ((row & 7) << 4)));
      }
    if (kt + 1 < NT) stA(nxt, 1, kt + 1);
    __builtin_amdgcn_s_barrier();
    __builtin_amdgcn_s_setprio(1);
#pragma unroll
    for (int mi = 0; mi < 4; ++mi)
#pragma unroll
      for (int nj = 0; nj < 2; ++nj)
#pragma unroll
        for (int ks = 0; ks < 2; ++ks)
          acc[mi][nj + 2] = MFMA16(aA[mi][ks], bB[nj][ks], acc[mi][nj + 2]);
    __builtin_amdgcn_s_setprio(0);
    __builtin_amdgcn_s_barrier();

    // ---- phase 2 ----
#pragma unroll
    for (int mi = 0; mi < 4; ++mi)
#pragma unroll
      for (int ks = 0; ks < 2; ++ks) {
        int row = 64 + mi * 16 + l15;
        int kk2 = (ks * 32 + lhi * 8) * 2;
        aB[mi][ks] = *(const bf16x8*)((const char*)Ab + row * 128 + (kk2 ^ ((row & 7) << 4)));
      }
    if (kt + 2 < NT) stB(cur, 0, kt + 2);
    __builtin_amdgcn_s_barrier();
    __builtin_amdgcn_s_setprio(1);
#pragma unroll
    for (int mi = 0; mi < 4; ++mi)
#pragma unroll
      for (int nj = 0; nj < 2; ++nj)
#pragma unroll
        for (int ks = 0; ks < 2; ++ks)
          acc[mi + 4][nj] = MFMA16(aB[mi][ks], bA[nj][ks], acc[mi + 4][nj]);
    __builtin_amdgcn_s_setprio(0);
    __builtin_amdgcn_s_barrier();

    // ---- phase 3 ----
    if (kt + 2 < NT) stB(cur, 1, kt + 2);
    __builtin_amdgcn_s_barrier();
    __builtin_amdgcn_s_setprio(1);
#pragma unroll
    for (int mi = 0; mi < 4; ++mi)
#pragma unroll
      for (int nj = 0; nj < 2; ++nj)
#pragma unroll
        for (int ks = 0; ks < 2; ++ks)
          acc[mi + 4][nj + 2] = MFMA16(aB[mi][ks], bB[nj][ks], acc[mi + 4][nj + 2]);
    __builtin_amdgcn_s_setprio(0);
    __builtin_amdgcn_s_barrier();
  }

  if constexpr (EPI == 3) {
    float* out = (float*)outp;
#pragma unroll
    for (int mi = 0; mi < 8; ++mi)
#pragma unroll
      for (int r = 0; r < 4; ++r) {
        size_t m = (size_t)(mbase + wm * 128 + mi * 16 + lhi * 4 + r);
#pragma unroll
        for (int nj = 0; nj < 4; ++nj) {
          int n = nbase + hib * 128 + (nj >> 1) * 64 + sub * 32 + (nj & 1) * 16 + l15;
          out[m * 4096 + n] = acc[mi][nj][r];
        }
      }
  } else {
    u16* qo = (u16*)outp;
    const int hgl = bx * 2 + hib;
#pragma unroll
    for (int mi = 0; mi < 8; ++mi)
#pragma unroll
      for (int r = 0; r < 4; ++r) {
        int m = mbase + wm * 128 + mi * 16 + lhi * 4 + r;
        int b = m >> 11, s = m & 2047;
        const float* ct = cost + (size_t)s * 64;
        const float* st = sint + (size_t)s * 64;
        size_t base = ((size_t)(b * 32 + hgl) * 2048 + s) * 128;
#pragma unroll
        for (int nj = 0; nj < 2; ++nj) {
          int d = sub * 32 + nj * 16 + l15;
          float c = ct[d], sn = st[d];
          float x1 = acc[mi][nj][r], x2 = acc[mi][nj + 2][r];
          qo[base + d] = f2b(x1 * c - x2 * sn);
          qo[base + d + 64] = f2b(x2 * c + x1 * sn);
        }
      }
  }
}

// ======== V GEMM, 256² tile / BK=32 / 4-phase quadrant schedule (gemm8 clone),
// split-bf16 (Ahi,Alo,Bhi,Blo staged), fused MXFP4 quant. 8 waves, 128KB LDS.
__global__ __launch_bounds__(512, 2) void k_gemmv4(const u16* __restrict__ ahi,
                                                   const u16* __restrict__ alo,
                                                   const u16* __restrict__ bhi,
                                                   const u16* __restrict__ blo,
                                                   u16* __restrict__ vt) {
  __shared__ u16 Ls[2][4][256 * 32];  // [buf][Ahi,Alo,Bhi,Blo][256 rows][32 k], 16KB each
  const int tid = threadIdx.x;
  const int wid = tid >> 6, lane = tid & 63;
  const int l15 = lane & 15, lhi = lane >> 4;
  const int wm = wid >> 2, wn = wid & 3;  // wm: 128-row half (quant block), wn: 64-col quarter
  const int bid = blockIdx.x;
  const int bx = 2 * (bid & 7) + (bid >> 7);
  const int by = (bid >> 3) & 15;
  const int mbase = by * 256, nbase = bx * 256;

  f32x4 acc[8][4];
#pragma unroll
  for (int mi = 0; mi < 8; ++mi)
#pragma unroll
    for (int nj = 0; nj < 4; ++nj) acc[mi][nj] = (f32x4){0.f, 0.f, 0.f, 0.f};

  auto stg = [&](int buf, int mat, int ktile, const u16* src, int rbase) {
    const int k0 = ktile * 32;
#pragma unroll
    for (int i = 0; i < 2; ++i) {
      int idx = i * 512 + tid;  // 0..1023 16B chunks
      int row = idx >> 2, slot = idx & 3;
      int sslot = slot ^ ((row >> 1) & 3);
      gload16(src + (size_t)(rbase + row) * 4096 + k0 + sslot * 8,
              (char*)Ls[buf][mat] + idx * 16);
    }
  };
  auto rd = [&](const u16* base, int row) -> bf16x8 {
    return *(const bf16x8*)((const char*)base + row * 64 + ((lhi ^ ((row >> 1) & 3)) << 4));
  };

  stg(0, 0, 0, ahi, mbase);
  stg(0, 1, 0, alo, mbase);
  stg(0, 2, 0, bhi, nbase);
  stg(0, 3, 0, blo, nbase);
  stg(1, 2, 1, bhi, nbase);
  stg(1, 3, 1, blo, nbase);

  const int NT = 128;
  for (int kt = 0; kt < NT; ++kt) {
    const int cur = kt & 1, nxt = cur ^ 1;
    const u16* AH = Ls[cur][0];
    const u16* AL = Ls[cur][1];
    const u16* BH = Ls[cur][2];
    const u16* BL = Ls[cur][3];
    bf16x8 axh[4], axl[4], ayh[4], ayl[4], bxh[2], bxl[2], byh[2], byl[2];

    // ---- phase 0 ----
    if (kt + 1 < NT) stg(nxt, 0, kt + 1, ahi, mbase);
    if (kt == NT - 1) {
      asm volatile("s_waitcnt vmcnt(0)" ::: "memory");
    } else {
      asm volatile("s_waitcnt vmcnt(6)" ::: "memory");
    }
    __builtin_amdgcn_s_barrier();
#pragma unroll
    for (int mi = 0; mi < 4; ++mi) {
      int row = wm * 128 + mi * 16 + l15;
      axh[mi] = rd(AH, row);
      axl[mi] = rd(AL, row);
    }
#pragma unroll
    for (int nj = 0; nj < 2; ++nj) {
      int row = wn * 64 + nj * 16 + l15;
      bxh[nj] = rd(BH, row);
      bxl[nj] = rd(BL, row);
    }
    __builtin_amdgcn_s_setprio(1);
#pragma unroll
    for (int mi = 0; mi < 4; ++mi)
#pragma unroll
      for (int nj = 0; nj < 2; ++nj) {
        acc[mi][nj] = MFMA16(axh[mi], bxh[nj], acc[mi][nj]);
        acc[mi][nj] = MFMA16(axh[mi], bxl[nj], acc[mi][nj]);
        acc[mi][nj] = MFMA16(axl[mi], bxh[nj], acc[mi][nj]);
      }
    __builtin_amdgcn_s_setprio(0);
    __builtin_amdgcn_s_barrier();

    // ---- phase 1 ----
#pragma unroll
    for (int nj = 0; nj < 2; ++nj) {
      int row = wn * 64 + 32 + nj * 16 + l15;
      byh[nj] = rd(BH, row);
      byl[nj] = rd(BL, row);
    }
    if (kt + 1 < NT) stg(nxt, 1, kt + 1, alo, mbase);
    __builtin_amdgcn_s_barrier();
    __builtin_amdgcn_s_setprio(1);
#pragma unroll
    for (int mi = 0; mi < 4; ++mi)
#pragma unroll
      for (int nj = 0; nj < 2; ++nj) {
        acc[mi][nj + 2] = MFMA16(axh[mi], byh[nj], acc[mi][nj + 2]);
        acc[mi][nj + 2] = MFMA16(axh[mi], byl[nj], acc[mi][nj + 2]);
        acc[mi][nj + 2] = MFMA16(axl[mi], byh[nj], acc[mi][nj + 2]);
      }
    __builtin_amdgcn_s_setprio(0);
    __builtin_amdgcn_s_barrier();

    // ---- phase 2 ----
#pragma unroll
    for (int mi = 0; mi < 4; ++mi) {
      int row = wm * 128 + 64 + mi * 16 + l15;
      ayh[mi] = rd(AH, row);
      ayl[mi] = rd(AL, row);
    }
    if (kt + 2 < NT) stg(cur, 2, kt + 2, bhi, nbase);
    __builtin_amdgcn_s_barrier();
    __builtin_amdgcn_s_setprio(1);
#pragma unroll
    for (int mi = 0; mi < 4; ++mi)
#pragma unroll
      for (int nj = 0; nj < 2; ++nj) {
        acc[mi + 4][nj] = MFMA16(ayh[mi], bxh[nj], acc[mi + 4][nj]);
        acc[mi + 4][nj] = MFMA16(ayh[mi], bxl[nj], acc[mi + 4][nj]);
        acc[mi + 4][nj] = MFMA16(ayl[mi], bxh[nj], acc[mi + 4][nj]);
      }
    __builtin_amdgcn_s_setprio(0);
    __builtin_amdgcn_s_barrier();

    // ---- phase 3 ----
    if (kt + 2 < NT) stg(cur, 3, kt + 2, blo, nbase);
    __builtin_amdgcn_s_barrier();
    __builtin_amdgcn_s_setprio(1);
#pragma unroll
    for (int mi = 0; mi < 4; ++mi)
#pragma unroll
      for (int nj = 0; nj < 2; ++nj) {
        acc[mi + 4][nj + 2] = MFMA16(ayh[mi], byh[nj], acc[mi + 4][nj + 2]);
        acc[mi + 4][nj + 2] = MFMA16(ayh[mi], byl[nj], acc[mi + 4][nj + 2]);
        acc[mi + 4][nj + 2] = MFMA16(ayl[mi], byh[nj], acc[mi + 4][nj + 2]);
      }
    __builtin_amdgcn_s_setprio(0);
    __builtin_amdgcn_s_barrier();
  }

  // ---- fused MXFP4 quant: wave's 128 rows == exactly one quant block -> wave-local amax ----
  const int h = (nbase >> 7) + (wn >> 1);
  const int d0 = (wn & 1) * 64;
#pragma unroll
  for (int nj = 0; nj < 4; ++nj) {
    float a = 0.f;
#pragma unroll
    for (int mi = 0; mi < 8; ++mi)
#pragma unroll
      for (int r = 0; r < 4; ++r) a = fmaxf(a, fabsf(acc[mi][nj][r]));
    a = fmaxf(a, __shfl_xor(a, 16));
    a = fmaxf(a, __shfl_xor(a, 32));
    float scale = 1.f, rs = 1.f;
    if (a > 0.f) {
      int e;
      float mant = frexpf(a, &e);
      int cc = (mant == 0.5f) ? (e - 1) : e;  // exact ceil(log2(amax))
      scale = ldexpf(1.f, cc - 3);
      rs = ldexpf(1.f, 3 - cc);
    }
    int d = d0 + nj * 16 + l15;
#pragma unroll
    for (int mi = 0; mi < 8; ++mi) {
      int m0 = mbase + wm * 128 + mi * 16 + lhi * 4;
      int b = m0 >> 11, s0 = m0 & 2047;
      uint2 pk;
      float v0 = quant1(acc[mi][nj][0], scale, rs);
      float v1 = quant1(acc[mi][nj][1], scale, rs);
      float v2 = quant1(acc[mi][nj][2], scale, rs);
      float v3 = quant1(acc[mi][nj][3], scale, rs);
      pk.x = (u32)f2b(v0) | ((u32)f2b(v1) << 16);
      pk.y = (u32)f2b(v2) | ((u32)f2b(v3) << 16);
      *(uint2*)(vt + ((size_t)(b * 32 + h) * 128 + d) * 2048 + s0) = pk;
    }
  }
}

// ======== FALLBACK PATH (used when ws_size is small) ========
template <int EPI>
__global__ __launch_bounds__(256) void k_gemm(const u16* __restrict__ A,
                                              const float* __restrict__ B,
                                              void* __restrict__ outp,
                                              const float* __restrict__ cost,
                                              const float* __restrict__ sint) {
  __shared__ u16 As[128 * 64];
  __shared__ u16 Bs[128 * 64];
  const int tid = threadIdx.x;
  const int w = tid >> 6, lane = tid & 63;
  const int l15 = lane & 15, lhi = lane >> 4;
  const int mbase = blockIdx.y * 128, nbase = blockIdx.x * 128;
  f32x4 acc[2][8];
#pragma unroll
  for (int i = 0; i < 2; ++i)
#pragma unroll
    for (int j = 0; j < 8; ++j) acc[i][j] = (f32x4){0.f, 0.f, 0.f, 0.f};

  const int brow = tid >> 1, bk = (tid & 1) * 32;
  const float* bsrc = B + (size_t)(nbase + brow) * 4096 + bk;

  for (int kt = 0; kt < 64; ++kt) {
    const int k0 = kt * 64;
#pragma unroll
    for (int i = 0; i < 4; ++i) {
      int idx = i * 256 + tid;
      int row = idx >> 3;
      int inb = ((idx & 7) << 4) ^ ((row & 7) << 4);
      gload16(A + (size_t)(mbase + row) * 4096 + (k0 + (inb >> 1)), (char*)As + idx * 16);
    }
    float4 bv[8];
    const float* bp = bsrc + k0;
#pragma unroll
    for (int c = 0; c < 8; ++c) bv[c] = *(const float4*)(bp + c * 4);
#pragma unroll
    for (int c = 0; c < 4; ++c) {
      uint4 pk;
      pk.x = (u32)f2b(bv[2 * c].x) | ((u32)f2b(bv[2 * c].y) << 16);
      pk.y = (u32)f2b(bv[2 * c].z) | ((u32)f2b(bv[2 * c].w) << 16);
      pk.z = (u32)f2b(bv[2 * c + 1].x) | ((u32)f2b(bv[2 * c + 1].y) << 16);
      pk.w = (u32)f2b(bv[2 * c + 1].z) | ((u32)f2b(bv[2 * c + 1].w) << 16);
      int byte = brow * 128 + (((bk + c * 8) * 2) ^ ((brow & 7) << 4));
      *(uint4*)((char*)Bs + byte) = pk;
    }
    __syncthreads();
#pragma unroll
    for (int ks = 0; ks < 2; ++ks) {
      const int kk2 = (ks * 32 + lhi * 8) * 2;
      bf16x8 af[2], bfr[8];
#pragma unroll
      for (int i = 0; i < 2; ++i) {
        int row = w * 32 + i * 16 + l15;
        af[i] = *(const bf16x8*)((const char*)As + row * 128 + (kk2 ^ ((row & 7) << 4)));
      }
#pragma unroll
      for (int j = 0; j < 8; ++j) {
        int row = j * 16 + l15;
        bfr[j] = *(const bf16x8*)((const char*)Bs + row * 128 + (kk2 ^ ((row & 7) << 4)));
      }
#pragma unroll
      for (int i = 0; i < 2; ++i)
#pragma unroll
        for (int j = 0; j < 8; ++j) acc[i][j] = MFMA16(af[i], bfr[j], acc[i][j]);
    }
    __syncthreads();
  }

  const int h = nbase >> 7;
  if constexpr (EPI == 3) {
    float* out = (float*)outp;
#pragma unroll
    for (int i = 0; i < 2; ++i)
#pragma unroll
      for (int r = 0; r < 4; ++r) {
        size_t m = (size_t)(mbase + w * 32 + i * 16 + lhi * 4 + r);
#pragma unroll
        for (int j = 0; j < 8; ++j) out[m * 4096 + nbase + j * 16 + l15] = acc[i][j][r];
      }
  } else {
    u16* qo = (u16*)outp;
#pragma unroll
    for (int i = 0; i < 2; ++i)
#pragma unroll
      for (int r = 0; r < 4; ++r) {
        int m = mbase + w * 32 + i * 16 + lhi * 4 + r;
        int b = m >> 11, s = m & 2047;
        const float* ct = cost + (size_t)s * 64;
        const float* st = sint + (size_t)s * 64;
        size_t base = ((size_t)(b * 32 + h) * 2048 + s) * 128;
#pragma unroll
        for (int j = 0; j < 4; ++j) {
          int d = j * 16 + l15;
          float c = ct[d], sn = st[d];
          float x1 = acc[i][j][r], x2 = acc[i][j + 4][r];
          qo[base + d] = f2b(x1 * c - x2 * sn);
          qo[base + d + 64] = f2b(x2 * c + x1 * sn);
        }
      }
  }
}

__global__ __launch_bounds__(256) void k_gemmv(const float* __restrict__ hsf,
                                               const float* __restrict__ Wv,
                                               u16* __restrict__ vt) {
  __shared__ u16 AsHi[128 * 64];
  __shared__ u16 AsLo[128 * 64];
  __shared__ u16 BsHi[128 * 64];
  __shared__ u16 BsLo[128 * 64];
  const int tid = threadIdx.x;
  const int w = tid >> 6, lane = tid & 63;
  const int l15 = lane & 15, lhi = lane >> 4;
  const int mbase = blockIdx.y * 128, nbase = blockIdx.x * 128;
  f32x4 acc[2][8];
#pragma unroll
  for (int i = 0; i < 2; ++i)
#pragma unroll
    for (int j = 0; j < 8; ++j) acc[i][j] = (f32x4){0.f, 0.f, 0.f, 0.f};

  const int srow = tid >> 1, sk = (tid & 1) * 32;
  const float* asrc = hsf + (size_t)(mbase + srow) * 4096 + sk;
  const float* bsrc = Wv + (size_t)(nbase + srow) * 4096 + sk;

  for (int kt = 0; kt < 64; ++kt) {
    const int k0 = kt * 64;
    float4 av[8], bv[8];
#pragma unroll
    for (int c = 0; c < 8; ++c) {
      av[c] = *(const float4*)(asrc + k0 + c * 4);
      bv[c] = *(const float4*)(bsrc + k0 + c * 4);
    }
#pragma unroll
    for (int c = 0; c < 4; ++c) {
      u16 h0, l0, h1, l1;
      float fa[8] = {av[2 * c].x, av[2 * c].y, av[2 * c].z, av[2 * c].w,
                     av[2 * c + 1].x, av[2 * c + 1].y, av[2 * c + 1].z, av[2 * c + 1].w};
      float fb[8] = {bv[2 * c].x, bv[2 * c].y, bv[2 * c].z, bv[2 * c].w,
                     bv[2 * c + 1].x, bv[2 * c + 1].y, bv[2 * c + 1].z, bv[2 * c + 1].w};
      u32 ph[4], pl[4], qh[4], ql[4];
#pragma unroll
      for (int t = 0; t < 4; ++t) {
        split2(fa[2 * t], h0, l0);
        split2(fa[2 * t + 1], h1, l1);
        ph[t] = (u32)h0 | ((u32)h1 << 16);
        pl[t] = (u32)l0 | ((u32)l1 << 16);
        split2(fb[2 * t], h0, l0);
        split2(fb[2 * t + 1], h1, l1);
        qh[t] = (u32)h0 | ((u32)h1 << 16);
        ql[t] = (u32)l0 | ((u32)l1 << 16);
      }
      int byte = srow * 128 + (((sk + c * 8) * 2) ^ ((srow & 7) << 4));
      *(uint4*)((char*)AsHi + byte) = make_uint4(ph[0], ph[1], ph[2], ph[3]);
      *(uint4*)((char*)AsLo + byte) = make_uint4(pl[0], pl[1], pl[2], pl[3]);
      *(uint4*)((char*)BsHi + byte) = make_uint4(qh[0], qh[1], qh[2], qh[3]);
      *(uint4*)((char*)BsLo + byte) = make_uint4(ql[0], ql[1], ql[2], ql[3]);
    }
    __syncthreads();
#pragma unroll
    for (int ks = 0; ks < 2; ++ks) {
      const int kk2 = (ks * 32 + lhi * 8) * 2;
      bf16x8 afh[2], afl[2];
#pragma unroll
      for (int i = 0; i < 2; ++i) {
        int row = w * 32 + i * 16 + l15;
        int off = row * 128 + (kk2 ^ ((row & 7) << 4));
        afh[i] = *(const bf16x8*)((const char*)AsHi + off);
        afl[i] = *(const bf16x8*)((const char*)AsLo + off);
      }
#pragma unroll
      for (int j = 0; j < 8; ++j) {
        int row = j * 16 + l15;
        int off = row * 128 + (kk2 ^ ((row & 7) << 4));
        bf16x8 bh = *(const bf16x8*)((const char*)BsHi + off);
        bf16x8 bl = *(const bf16x8*)((const char*)BsLo + off);
#pragma unroll
        for (int i = 0; i < 2; ++i) {
          acc[i][j] = MFMA16(afh[i], bh, acc[i][j]);
          acc[i][j] = MFMA16(afh[i], bl, acc[i][j]);
          acc[i][j] = MFMA16(afl[i], bh, acc[i][j]);
        }
      }
    }
    __syncthreads();
  }

  const int h = nbase >> 7;
  float pam[8];
#pragma unroll
  for (int j = 0; j < 8; ++j) {
    float a = 0.f;
#pragma unroll
    for (int i = 0; i < 2; ++i)
#pragma unroll
      for (int r = 0; r < 4; ++r) a = fmaxf(a, fabsf(acc[i][j][r]));
    a = fmaxf(a, __shfl_xor(a, 16));
    a = fmaxf(a, __shfl_xor(a, 32));
    pam[j] = a;
  }
  float* red = (float*)BsHi;
  if (lhi == 0) {
#pragma unroll
    for (int j = 0; j < 8; ++j) red[w * 128 + j * 16 + l15] = pam[j];
  }
  __syncthreads();
#pragma unroll
  for (int j = 0; j < 8; ++j) {
    float amax = fmaxf(fmaxf(red[0 * 128 + j * 16 + l15], red[1 * 128 + j * 16 + l15]),
                       fmaxf(red[2 * 128 + j * 16 + l15], red[3 * 128 + j * 16 + l15]));
    float scale = 1.f, rs = 1.f;
    if (amax > 0.f) {
      int e;
      float mant = frexpf(amax, &e);
      int c = (mant == 0.5f) ? (e - 1) : e;
      scale = ldexpf(1.f, c - 3);
      rs = ldexpf(1.f, 3 - c);
    }
#pragma unroll
    for (int i = 0; i < 2; ++i) {
      int m0 = mbase + w * 32 + i * 16 + lhi * 4;
      int b = m0 >> 11, s0 = m0 & 2047;
      int d = j * 16 + l15;
      uint2 pk;
      float v0 = quant1(acc[i][j][0], scale, rs);
      float v1 = quant1(acc[i][j][1], scale, rs);
      float v2 = quant1(acc[i][j][2], scale, rs);
      float v3 = quant1(acc[i][j][3], scale, rs);
      pk.x = (u32)f2b(v0) | ((u32)f2b(v1) << 16);
      pk.y = (u32)f2b(v2) | ((u32)f2b(v3) << 16);
      *(uint2*)(vt + ((size_t)(b * 32 + h) * 128 + d) * 2048 + s0) = pk;
    }
  }
}

// ---------------- R10 flash attention (causal): QB=128 (8 waves), KB=64 — R8 structure,
// LDS trimmed to exactly 80KB (Ps [16][64] XOR-swizzled) + VGPR<=128 -> 2 blocks/CU.
__global__ __launch_bounds__(512, 4) void k_attn(const u16* __restrict__ qg,
                                                 const u16* __restrict__ kg,
                                                 const u16* __restrict__ vtg,
                                                 u16* __restrict__ ao) {
  __shared__ u16 Ks[2][64 * 128];  // 32KB: [kk][d], 256B rows, swizzled by ((row&15)<<4)
  __shared__ u16 Vs[2][128 * 64];  // 32KB: [d][s], 128B rows, swizzled by ((row&7)<<4)
  __shared__ u16 Ps[8 * 16 * 64];  // 16KB: per-wave P [16][64], byte ^= ((row&7)<<4)
  const int qt = 15 - blockIdx.y;  // longest blocks dispatch first
  const int bh = blockIdx.x;
  const int tid = threadIdx.x, w = tid >> 6, lane = tid & 63;
  const int l15 = lane & 15, lhi = lane >> 4;
  const size_t bhoff = (size_t)bh * (2048 * 128);
  const float SC = 0.08838834764831845f;  // 1/sqrt(128)

  bf16x8 qf[4];
  {
    const int qrow = qt * 128 + w * 16 + l15;
    const u16* qp = qg + bhoff + (size_t)qrow * 128 + lhi * 8;
#pragma unroll
    for (int ks = 0; ks < 4; ++ks) qf[ks] = *(const bf16x8*)(qp + ks * 32);
  }
  f32x4 oacc[8];
#pragma unroll
  for (int dt = 0; dt < 8; ++dt) oacc[dt] = (f32x4){0.f, 0.f, 0.f, 0.f};
  float mrow[4] = {-1e30f, -1e30f, -1e30f, -1e30f};
  float lrow[4] = {0.f, 0.f, 0.f, 0.f};

  auto stage = [&](int buf, int kbase) {
#pragma unroll
    for (int i = 0; i < 2; ++i) {
      int idx = i * 512 + tid;
      int row = idx >> 4;
      int inb = ((idx & 15) << 4) ^ ((row & 15) << 4);
      gload16(kg + bhoff + (size_t)(kbase + row) * 128 + (inb >> 1), (char*)Ks[buf] + idx * 16);
    }
#pragma unroll
    for (int i = 0; i < 2; ++i) {
      int idx = i * 512 + tid;
      int row = idx >> 3;
      int inb = ((idx & 7) << 4) ^ ((row & 7) << 4);
      gload16(vtg + bhoff + (size_t)row * 2048 + kbase + (inb >> 1), (char*)Vs[buf] + idx * 16);
    }
  };

  const int nt = 2 * qt + 2;
  stage(0, 0);

  for (int kt = 0; kt < nt; ++kt) {
    const int cur = kt & 1;
    if (kt < nt - 1) {
      stage(cur ^ 1, (kt + 1) * 64);
      asm volatile("s_waitcnt vmcnt(4)" ::: "memory");
    } else {
      asm volatile("s_waitcnt vmcnt(0)" ::: "memory");
    }
    __builtin_amdgcn_s_barrier();

    f32x4 sc4[4];
#pragma unroll
    for (int j = 0; j < 4; ++j) sc4[j] = (f32x4){0.f, 0.f, 0.f, 0.f};
#pragma unroll
    for (int ks = 0; ks < 4; ++ks) {
      const int db = (ks * 32 + lhi * 8) * 2;
#pragma unroll
      for (int j = 0; j < 4; ++j) {
        int kr = j * 16 + l15;
        bf16x8 bfr = *(const bf16x8*)((const char*)Ks[cur] + kr * 256 + (db ^ ((kr & 15) << 4)));
        sc4[j] = MFMA16(qf[ks], bfr, sc4[j]);
      }
    }
    float p[4][4];
    const int kbase = kt * 64;
    const bool tail = (kt >= 2 * qt);
#pragma unroll
    for (int j = 0; j < 4; ++j)
#pragma unroll
      for (int r = 0; r < 4; ++r) {
        float s = sc4[j][r] * SC;
        if (tail && (kbase + j * 16 + l15 > qt * 128 + w * 16 + lhi * 4 + r)) s = -1e9f;
        p[j][r] = s;
      }
    float alpha[4];
#pragma unroll
    for (int r = 0; r < 4; ++r) {
      float tm = fmaxf(fmaxf(p[0][r], p[1][r]), fmaxf(p[2][r], p[3][r]));
      tm = fmaxf(tm, __shfl_xor(tm, 1));
      tm = fmaxf(tm, __shfl_xor(tm, 2));
      tm = fmaxf(tm, __shfl_xor(tm, 4));
      tm = fmaxf(tm, __shfl_xor(tm, 8));
      float mn = fmaxf(mrow[r], tm);
      alpha[r] = __expf(mrow[r] - mn);
      mrow[r] = mn;
      float rsum = 0.f;
#pragma unroll
      for (int j = 0; j < 4; ++j) {
        float e = __expf(p[j][r] - mn);
        p[j][r] = e;
        rsum += e;
      }
      rsum += __shfl_xor(rsum, 1);
      rsum += __shfl_xor(rsum, 2);
      rsum += __shfl_xor(rsum, 4);
      rsum += __shfl_xor(rsum, 8);
      lrow[r] = lrow[r] * alpha[r] + rsum;
    }
#pragma unroll
    for (int dt = 0; dt < 8; ++dt) {
      f32x4 t = oacc[dt];
      t[0] *= alpha[0]; t[1] *= alpha[1]; t[2] *= alpha[2]; t[3] *= alpha[3];
      oacc[dt] = t;
    }
    // P -> per-wave LDS [16][64], byte ^= ((row&7)<<4); bijective, <=2-way conflicts
#pragma unroll
    for (int j = 0; j < 4; ++j)
#pragma unroll
      for (int r = 0; r < 4; ++r) {
        int row = lhi * 4 + r;
        *(u16*)((char*)Ps + w * 2048 + row * 128 + (((j * 16 + l15) * 2) ^ ((row & 7) << 4))) =
            f2b(p[j][r]);
      }
#pragma unroll
    for (int ks2 = 0; ks2 < 2; ++ks2) {
      const int sb = ks2 * 32 + lhi * 8;
      bf16x8 pa = *(const bf16x8*)((const char*)Ps + w * 2048 + l15 * 128 +
                                   ((sb * 2) ^ ((l15 & 7) << 4)));
#pragma unroll
      for (int dt = 0; dt < 8; ++dt) {
        int d = dt * 16 + l15;
        bf16x8 vb = *(const bf16x8*)((const char*)Vs[cur] + d * 128 + ((sb * 2) ^ ((d & 7) << 4)));
        oacc[dt] = MFMA16(pa, vb, oacc[dt]);
      }
    }
    asm volatile("s_waitcnt lgkmcnt(0)" ::: "memory");
    __builtin_amdgcn_s_barrier();
  }

  const int b = bh >> 5, h = bh & 31;
  float inv[4];
#pragma unroll
  for (int r = 0; r < 4; ++r) inv[r] = 1.f / lrow[r];
#pragma unroll
  for (int dt = 0; dt < 8; ++dt)
#pragma unroll
    for (int r = 0; r < 4; ++r) {
      int s = qt * 128 + w * 16 + lhi * 4 + r;
      ao[((size_t)(b * 2048 + s)) * 4096 + h * 128 + dt * 16 + l15] = f2b(oacc[dt][r] * inv[r]);
    }
}

extern "C" void kernel_launch(void* const* d_in, const int* in_sizes, int n_in,
                              void* d_out, int out_size, void* d_ws, size_t ws_size,
                              hipStream_t stream) {
  (void)in_sizes; (void)n_in; (void)out_size;
  const float* hs = (const float*)d_in[0];
  const int* pid = (const int*)d_in[1];
  const float* Wq = (const float*)d_in[2];
  const float* Wk = (const float*)d_in[3];
  const float* Wv = (const float*)d_in[4];
  const float* Wo = (const float*)d_in[5];
  float* out = (float*)d_out;
  char* ws = (char*)d_ws;

  const size_t BUF = 33554432;  // one 4096x4096 bf16 buffer
  const size_t NEED = 7 * BUF + 2 * 524288;

  if (ws_size >= NEED) {
    u16* hsb  = (u16*)(ws + 0 * BUF);          // hs hi
    u16* hslo = (u16*)(ws + 1 * BUF);          // hs lo; later aob
    u16* qb   = (u16*)(ws + 2 * BUF);
    u16* kb   = (u16*)(ws + 3 * BUF);
    u16* vtb  = (u16*)(ws + 4 * BUF);
    u16* wbuf = (u16*)(ws + 5 * BUF);          // Wq_b -> Wk_b -> Wv_hi -> Wo_b (sequential)
    u16* wvlo = (u16*)(ws + 6 * BUF);
    float* cost = (float*)(ws + 7 * BUF);
    float* sint = (float*)(ws + 7 * BUF + 524288);
    u16* aob = hslo;

    k_splt<<<16384, 256, 0, stream>>>(hs, hsb, hslo);
    k_rope_tab<<<512, 256, 0, stream>>>(pid, cost, sint);
    k_cvt<<<16384, 256, 0, stream>>>(Wq, wbuf);
    k_gemm8<0><<<256, 512, 0, stream>>>(hsb, wbuf, (void*)qb, cost, sint);
    k_cvt<<<16384, 256, 0, stream>>>(Wk, wbuf);
    k_gemm8<1><<<256, 512, 0, stream>>>(hsb, wbuf, (void*)kb, cost, sint);
    k_splt<<<16384, 256, 0, stream>>>(Wv, wbuf, wvlo);
    k_gemmv4<<<256, 512, 0, stream>>>(hsb, hslo, wbuf, wvlo, vtb);
    k_attn<<<dim3(64, 16), 512, 0, stream>>>(qb, kb, vtb, aob);
    k_cvt<<<16384, 256, 0, stream>>>(Wo, wbuf);
    k_gemm8<3><<<256, 512, 0, stream>>>(aob, wbuf, (void*)out, nullptr, nullptr);
  } else {
    u16* hsb = (u16*)(ws + 0);
    u16* qb  = (u16*)(ws + 33554432);
    u16* kb  = (u16*)(ws + 67108864);
    u16* vtb = (u16*)(ws + 100663296);
    float* cost = (float*)(ws + 134217728);
    float* sint = (float*)(ws + 134742016);
    u16* aob = hsb;

    k_cvt<<<16384, 256, 0, stream>>>(hs, hsb);
    k_rope_tab<<<512, 256, 0, stream>>>(pid, cost, sint);
    k_gemm<0><<<dim3(32, 32), 256, 0, stream>>>(hsb, Wq, (void*)qb, cost, sint);
    k_gemm<1><<<dim3(32, 32), 256, 0, stream>>>(hsb, Wk, (void*)kb, cost, sint);
    k_gemmv<<<dim3(32, 32), 256, 0, stream>>>(hs, Wv, vtb);
    k_attn<<<dim3(64, 16), 512, 0, stream>>>(qb, kb, vtb, aob);
    k_gemm<3><<<dim3(32, 32), 256, 0, stream>>>(aob, Wo, (void*)out, nullptr, nullptr);
  }
}

// Round 11
// 846.298 us; speedup vs baseline: 1.0899x; 1.0402x over previous
//
#include <hip/hip_runtime.h>
#include <math.h>

typedef unsigned short u16;
typedef unsigned int u32;
typedef short bf16x8 __attribute__((ext_vector_type(8)));
typedef float f32x4 __attribute__((ext_vector_type(4)));

#define MFMA16(a, b, c) __builtin_amdgcn_mfma_f32_16x16x32_bf16(a, b, c, 0, 0, 0)

static __device__ __forceinline__ u16 f2b(float f) {
  u32 u = __builtin_bit_cast(u32, f);
  u = (u + 0x7fffu + ((u >> 16) & 1u)) >> 16;
  return (u16)u;
}
static __device__ __forceinline__ float b2f(u16 h) {
  return __builtin_bit_cast(float, ((u32)h) << 16);
}
static __device__ __forceinline__ void gload16(const void* g, void* l) {
  __builtin_amdgcn_global_load_lds((const __attribute__((address_space(1))) void*)g,
                                   (__attribute__((address_space(3))) void*)l, 16, 0, 0);
}
// split f32 into hi-bf16 + lo-bf16 (x ~= hi + lo, rel err ~2^-18)
static __device__ __forceinline__ void split2(float x, u16& hi, u16& lo) {
  hi = f2b(x);
  lo = f2b(x - b2f(hi));
}
static __device__ __forceinline__ float quant1(float x, float scale, float rs) {
  float y = fabsf(x) * rs;
  float st = y < 2.f ? 0.5f : (y < 4.f ? 1.f : 2.f);
  float iv = y < 2.f ? 2.f : (y < 4.f ? 1.f : 0.5f);
  float q = fminf(rintf(y * iv) * st, 6.f);  // rintf = RNE = jnp.round
  return copysignf(q * scale, x);
}

// ---------------- f32 -> bf16 convert ----------------
__global__ __launch_bounds__(256) void k_cvt(const float* __restrict__ in, u16* __restrict__ out) {
  int i = blockIdx.x * 256 + threadIdx.x;
  float4 v = ((const float4*)in)[i];
  u32 lo = (u32)f2b(v.x) | ((u32)f2b(v.y) << 16);
  u32 hi = (u32)f2b(v.z) | ((u32)f2b(v.w) << 16);
  ((uint2*)out)[i] = make_uint2(lo, hi);
}

// ---------------- f32 -> (hi,lo) bf16 split ----------------
__global__ __launch_bounds__(256) void k_splt(const float* __restrict__ in,
                                              u16* __restrict__ hi, u16* __restrict__ lo) {
  int i = blockIdx.x * 256 + threadIdx.x;
  float4 v = ((const float4*)in)[i];
  u16 h[4], l[4];
  split2(v.x, h[0], l[0]);
  split2(v.y, h[1], l[1]);
  split2(v.z, h[2], l[2]);
  split2(v.w, h[3], l[3]);
  ((uint2*)hi)[i] = make_uint2((u32)h[0] | ((u32)h[1] << 16), (u32)h[2] | ((u32)h[3] << 16));
  ((uint2*)lo)[i] = make_uint2((u32)l[0] | ((u32)l[1] << 16), (u32)l[2] | ((u32)l[3] << 16));
}

// ---------------- rope tables: [2048][64] cos & sin ----------------
__global__ __launch_bounds__(256) void k_rope_tab(const int* __restrict__ pid,
                                                  float* __restrict__ ct,
                                                  float* __restrict__ st) {
  int t = blockIdx.x * 256 + threadIdx.x;  // 131072 total
  int s = t >> 6, i = t & 63;
  float inv = powf(10000.f, -(float)i * (1.f / 64.f));
  float a = (float)pid[s] * inv;
  ct[t] = cosf(a);
  st[t] = sinf(a);
}

// ======== 256x256 8-phase bf16 GEMM (T2+T3+T4+T5), both operands gload_lds ========
// C[4096][4096] = A(bf16,[M][K]) * B(bf16,[N][K])^T, BK=64, 8 waves.
// EPI 0/1: rope -> (b,h,s,d) bf16 ; EPI 3: f32 -> d_out.
template <int EPI>
__global__ __launch_bounds__(512, 2) void k_gemm8(const u16* __restrict__ A,
                                                  const u16* __restrict__ B,
                                                  void* __restrict__ outp,
                                                  const float* __restrict__ cost,
                                                  const float* __restrict__ sint) {
  __shared__ u16 Ls[2][2][2][8192];  // [buf][A=0/B=1][half][128*64], 16KB each, 128KB total
  const int tid = threadIdx.x;
  const int wid = tid >> 6, lane = tid & 63;
  const int l15 = lane & 15, lhi = lane >> 4;
  const int wm = wid >> 2, wn = wid & 3;
  const int hib = wn >> 1, sub = wn & 1;

  const int bid = blockIdx.x;
  const int bx = 2 * (bid & 7) + (bid >> 7);   // N-block 0..15
  const int by = (bid >> 3) & 15;              // M-block 0..15
  const int mbase = by * 256, nbase = bx * 256;

  f32x4 acc[8][4];
#pragma unroll
  for (int mi = 0; mi < 8; ++mi)
#pragma unroll
    for (int nj = 0; nj < 4; ++nj) acc[mi][nj] = (f32x4){0.f, 0.f, 0.f, 0.f};

  auto stA = [&](int buf, int half, int ktile) {
    u16* dst = Ls[buf][0][half];
    const int k0 = ktile * 64;
#pragma unroll
    for (int i = 0; i < 2; ++i) {
      int idx = i * 512 + tid;
      int row = idx >> 3;
      int col = k0 + ((((idx & 7) << 4) ^ ((row & 7) << 4)) >> 1);
      gload16(A + (size_t)(mbase + half * 128 + row) * 4096 + col, (char*)dst + idx * 16);
    }
  };
  auto stB = [&](int buf, int half, int ktile) {
    u16* dst = Ls[buf][1][half];
    const int k0 = ktile * 64;
#pragma unroll
    for (int i = 0; i < 2; ++i) {
      int idx = i * 512 + tid;
      int row = idx >> 3;
      int col = k0 + ((((idx & 7) << 4) ^ ((row & 7) << 4)) >> 1);
      gload16(B + (size_t)(nbase + half * 128 + row) * 4096 + col, (char*)dst + idx * 16);
    }
  };

  stB(0, 0, 0);
  stB(0, 1, 0);
  stA(0, 0, 0);
  stA(0, 1, 0);
  stB(1, 0, 1);
  stB(1, 1, 1);

  const int NT = 64;
  for (int kt = 0; kt < NT; ++kt) {
    const int cur = kt & 1, nxt = cur ^ 1;
    const u16* Ab = Ls[cur][0][wm];
    const u16* Bb = Ls[cur][1][hib];
    bf16x8 aA[4][2], aB[4][2], bA[2][2], bB[2][2];

    // ---- phase 0 ----
    if (kt + 1 < NT) stA(nxt, 0, kt + 1);
    if (kt == NT - 1) {
      asm volatile("s_waitcnt vmcnt(0)" ::: "memory");
    } else {
      asm volatile("s_waitcnt vmcnt(6)" ::: "memory");
    }
    __builtin_amdgcn_s_barrier();
#pragma unroll
    for (int mi = 0; mi < 4; ++mi)
#pragma unroll
      for (int ks = 0; ks < 2; ++ks) {
        int row = mi * 16 + l15;
        int kk2 = (ks * 32 + lhi * 8) * 2;
        aA[mi][ks] = *(const bf16x8*)((const char*)Ab + row * 128 + (kk2 ^ ((row & 7) << 4)));
      }
#pragma unroll
    for (int nj = 0; nj < 2; ++nj)
#pragma unroll
      for (int ks = 0; ks < 2; ++ks) {
        int row = sub * 32 + nj * 16 + l15;
        int kk2 = (ks * 32 + lhi * 8) * 2;
        bA[nj][ks] = *(const bf16x8*)((const char*)Bb + row * 128 + (kk2 ^ ((row & 7) << 4)));
      }
    __builtin_amdgcn_s_setprio(1);
#pragma unroll
    for (int mi = 0; mi < 4; ++mi)
#pragma unroll
      for (int nj = 0; nj < 2; ++nj)
#pragma unroll
        for (int ks = 0; ks < 2; ++ks) acc[mi][nj] = MFMA16(aA[mi][ks], bA[nj][ks], acc[mi][nj]);
    __builtin_amdgcn_s_setprio(0);
    __builtin_amdgcn_s_barrier();

    // ---- phase 1 ----
#pragma unroll
    for (int nj = 0; nj < 2; ++nj)
#pragma unroll
      for (int ks = 0; ks < 2; ++ks) {
        int row = 64 + sub * 32 + nj * 16 + l15;
        int kk2 = (ks * 32 + lhi * 8) * 2;
        bB[nj][ks] = *(const bf16x8*)((const char*)Bb + row * 128 + (kk2 ^ ((row & 7) << 4)));
      }
    if (kt + 1 < NT) stA(nxt, 1, kt + 1);
    __builtin_amdgcn_s_barrier();
    __builtin_amdgcn_s_setprio(1);
#pragma unroll
    for (int mi = 0; mi < 4; ++mi)
#pragma unroll
      for (int nj = 0; nj < 2; ++nj)
#pragma unroll
        for (int ks = 0; ks < 2; ++ks)
          acc[mi][nj + 2] = MFMA16(aA[mi][ks], bB[nj][ks], acc[mi][nj + 2]);
    __builtin_amdgcn_s_setprio(0);
    __builtin_amdgcn_s_barrier();

    // ---- phase 2 ----
#pragma unroll
    for (int mi = 0; mi < 4; ++mi)
#pragma unroll
      for (int ks = 0; ks < 2; ++ks) {
        int row = 64 + mi * 16 + l15;
        int kk2 = (ks * 32 + lhi * 8) * 2;
        aB[mi][ks] = *(const bf16x8*)((const char*)Ab + row * 128 + (kk2 ^ ((row & 7) << 4)));
      }
    if (kt + 2 < NT) stB(cur, 0, kt + 2);
    __builtin_amdgcn_s_barrier();
    __builtin_amdgcn_s_setprio(1);
#pragma unroll
    for (int mi = 0; mi < 4; ++mi)
#pragma unroll
      for (int nj = 0; nj < 2; ++nj)
#pragma unroll
        for (int ks = 0; ks < 2; ++ks)
          acc[mi + 4][nj] = MFMA16(aB[mi][ks], bA[nj][ks], acc[mi + 4][nj]);
    __builtin_amdgcn_s_setprio(0);
    __builtin_amdgcn_s_barrier();

    // ---- phase 3 ----
    if (kt + 2 < NT) stB(cur, 1, kt + 2);
    __builtin_amdgcn_s_barrier();
    __builtin_amdgcn_s_setprio(1);
#pragma unroll
    for (int mi = 0; mi < 4; ++mi)
#pragma unroll
      for (int nj = 0; nj < 2; ++nj)
#pragma unroll
        for (int ks = 0; ks < 2; ++ks)
          acc[mi + 4][nj + 2] = MFMA16(aB[mi][ks], bB[nj][ks], acc[mi + 4][nj + 2]);
    __builtin_amdgcn_s_setprio(0);
    __builtin_amdgcn_s_barrier();
  }

  if constexpr (EPI == 3) {
    float* out = (float*)outp;
#pragma unroll
    for (int mi = 0; mi < 8; ++mi)
#pragma unroll
      for (int r = 0; r < 4; ++r) {
        size_t m = (size_t)(mbase + wm * 128 + mi * 16 + lhi * 4 + r);
#pragma unroll
        for (int nj = 0; nj < 4; ++nj) {
          int n = nbase + hib * 128 + (nj >> 1) * 64 + sub * 32 + (nj & 1) * 16 + l15;
          out[m * 4096 + n] = acc[mi][nj][r];
        }
      }
  } else {
    u16* qo = (u16*)outp;
    const int hgl = bx * 2 + hib;
#pragma unroll
    for (int mi = 0; mi < 8; ++mi)
#pragma unroll
      for (int r = 0; r < 4; ++r) {
        int m = mbase + wm * 128 + mi * 16 + lhi * 4 + r;
        int b = m >> 11, s = m & 2047;
        const float* ct = cost + (size_t)s * 64;
        const float* st = sint + (size_t)s * 64;
        size_t base = ((size_t)(b * 32 + hgl) * 2048 + s) * 128;
#pragma unroll
        for (int nj = 0; nj < 2; ++nj) {
          int d = sub * 32 + nj * 16 + l15;
          float c = ct[d], sn = st[d];
          float x1 = acc[mi][nj][r], x2 = acc[mi][nj + 2][r];
          qo[base + d] = f2b(x1 * c - x2 * sn);
          qo[base + d + 64] = f2b(x2 * c + x1 * sn);
        }
      }
  }
}

// ======== V GEMM, 256² tile / BK=32 / 4-phase quadrant schedule (gemm8 clone),
// split-bf16 (Ahi,Alo,Bhi,Blo staged), fused MXFP4 quant. 8 waves, 128KB LDS.
__global__ __launch_bounds__(512, 2) void k_gemmv4(const u16* __restrict__ ahi,
                                                   const u16* __restrict__ alo,
                                                   const u16* __restrict__ bhi,
                                                   const u16* __restrict__ blo,
                                                   u16* __restrict__ vt) {
  __shared__ u16 Ls[2][4][256 * 32];  // [buf][Ahi,Alo,Bhi,Blo][256 rows][32 k], 16KB each
  const int tid = threadIdx.x;
  const int wid = tid >> 6, lane = tid & 63;
  const int l15 = lane & 15, lhi = lane >> 4;
  const int wm = wid >> 2, wn = wid & 3;  // wm: 128-row half (quant block), wn: 64-col quarter
  const int bid = blockIdx.x;
  const int bx = 2 * (bid & 7) + (bid >> 7);
  const int by = (bid >> 3) & 15;
  const int mbase = by * 256, nbase = bx * 256;

  f32x4 acc[8][4];
#pragma unroll
  for (int mi = 0; mi < 8; ++mi)
#pragma unroll
    for (int nj = 0; nj < 4; ++nj) acc[mi][nj] = (f32x4){0.f, 0.f, 0.f, 0.f};

  auto stg = [&](int buf, int mat, int ktile, const u16* src, int rbase) {
    const int k0 = ktile * 32;
#pragma unroll
    for (int i = 0; i < 2; ++i) {
      int idx = i * 512 + tid;  // 0..1023 16B chunks
      int row = idx >> 2, slot = idx & 3;
      int sslot = slot ^ ((row >> 1) & 3);
      gload16(src + (size_t)(rbase + row) * 4096 + k0 + sslot * 8,
              (char*)Ls[buf][mat] + idx * 16);
    }
  };
  auto rd = [&](const u16* base, int row) -> bf16x8 {
    return *(const bf16x8*)((const char*)base + row * 64 + ((lhi ^ ((row >> 1) & 3)) << 4));
  };

  stg(0, 0, 0, ahi, mbase);
  stg(0, 1, 0, alo, mbase);
  stg(0, 2, 0, bhi, nbase);
  stg(0, 3, 0, blo, nbase);
  stg(1, 2, 1, bhi, nbase);
  stg(1, 3, 1, blo, nbase);

  const int NT = 128;
  for (int kt = 0; kt < NT; ++kt) {
    const int cur = kt & 1, nxt = cur ^ 1;
    const u16* AH = Ls[cur][0];
    const u16* AL = Ls[cur][1];
    const u16* BH = Ls[cur][2];
    const u16* BL = Ls[cur][3];
    bf16x8 axh[4], axl[4], ayh[4], ayl[4], bxh[2], bxl[2], byh[2], byl[2];

    // ---- phase 0 ----
    if (kt + 1 < NT) stg(nxt, 0, kt + 1, ahi, mbase);
    if (kt == NT - 1) {
      asm volatile("s_waitcnt vmcnt(0)" ::: "memory");
    } else {
      asm volatile("s_waitcnt vmcnt(6)" ::: "memory");
    }
    __builtin_amdgcn_s_barrier();
#pragma unroll
    for (int mi = 0; mi < 4; ++mi) {
      int row = wm * 128 + mi * 16 + l15;
      axh[mi] = rd(AH, row);
      axl[mi] = rd(AL, row);
    }
#pragma unroll
    for (int nj = 0; nj < 2; ++nj) {
      int row = wn * 64 + nj * 16 + l15;
      bxh[nj] = rd(BH, row);
      bxl[nj] = rd(BL, row);
    }
    __builtin_amdgcn_s_setprio(1);
#pragma unroll
    for (int mi = 0; mi < 4; ++mi)
#pragma unroll
      for (int nj = 0; nj < 2; ++nj) {
        acc[mi][nj] = MFMA16(axh[mi], bxh[nj], acc[mi][nj]);
        acc[mi][nj] = MFMA16(axh[mi], bxl[nj], acc[mi][nj]);
        acc[mi][nj] = MFMA16(axl[mi], bxh[nj], acc[mi][nj]);
      }
    __builtin_amdgcn_s_setprio(0);
    __builtin_amdgcn_s_barrier();

    // ---- phase 1 ----
#pragma unroll
    for (int nj = 0; nj < 2; ++nj) {
      int row = wn * 64 + 32 + nj * 16 + l15;
      byh[nj] = rd(BH, row);
      byl[nj] = rd(BL, row);
    }
    if (kt + 1 < NT) stg(nxt, 1, kt + 1, alo, mbase);
    __builtin_amdgcn_s_barrier();
    __builtin_amdgcn_s_setprio(1);
#pragma unroll
    for (int mi = 0; mi < 4; ++mi)
#pragma unroll
      for (int nj = 0; nj < 2; ++nj) {
        acc[mi][nj + 2] = MFMA16(axh[mi], byh[nj], acc[mi][nj + 2]);
        acc[mi][nj + 2] = MFMA16(axh[mi], byl[nj], acc[mi][nj + 2]);
        acc[mi][nj + 2] = MFMA16(axl[mi], byh[nj], acc[mi][nj + 2]);
      }
    __builtin_amdgcn_s_setprio(0);
    __builtin_amdgcn_s_barrier();

    // ---- phase 2 ----
#pragma unroll
    for (int mi = 0; mi < 4; ++mi) {
      int row = wm * 128 + 64 + mi * 16 + l15;
      ayh[mi] = rd(AH, row);
      ayl[mi] = rd(AL, row);
    }
    if (kt + 2 < NT) stg(cur, 2, kt + 2, bhi, nbase);
    __builtin_amdgcn_s_barrier();
    __builtin_amdgcn_s_setprio(1);
#pragma unroll
    for (int mi = 0; mi < 4; ++mi)
#pragma unroll
      for (int nj = 0; nj < 2; ++nj) {
        acc[mi + 4][nj] = MFMA16(ayh[mi], bxh[nj], acc[mi + 4][nj]);
        acc[mi + 4][nj] = MFMA16(ayh[mi], bxl[nj], acc[mi + 4][nj]);
        acc[mi + 4][nj] = MFMA16(ayl[mi], bxh[nj], acc[mi + 4][nj]);
      }
    __builtin_amdgcn_s_setprio(0);
    __builtin_amdgcn_s_barrier();

    // ---- phase 3 ----
    if (kt + 2 < NT) stg(cur, 3, kt + 2, blo, nbase);
    __builtin_amdgcn_s_barrier();
    __builtin_amdgcn_s_setprio(1);
#pragma unroll
    for (int mi = 0; mi < 4; ++mi)
#pragma unroll
      for (int nj = 0; nj < 2; ++nj) {
        acc[mi + 4][nj + 2] = MFMA16(ayh[mi], byh[nj], acc[mi + 4][nj + 2]);
        acc[mi + 4][nj + 2] = MFMA16(ayh[mi], byl[nj], acc[mi + 4][nj + 2]);
        acc[mi + 4][nj + 2] = MFMA16(ayl[mi], byh[nj], acc[mi + 4][nj + 2]);
      }
    __builtin_amdgcn_s_setprio(0);
    __builtin_amdgcn_s_barrier();
  }

  // ---- fused MXFP4 quant: wave's 128 rows == exactly one quant block -> wave-local amax ----
  const int h = (nbase >> 7) + (wn >> 1);
  const int d0 = (wn & 1) * 64;
#pragma unroll
  for (int nj = 0; nj < 4; ++nj) {
    float a = 0.f;
#pragma unroll
    for (int mi = 0; mi < 8; ++mi)
#pragma unroll
      for (int r = 0; r < 4; ++r) a = fmaxf(a, fabsf(acc[mi][nj][r]));
    a = fmaxf(a, __shfl_xor(a, 16));
    a = fmaxf(a, __shfl_xor(a, 32));
    float scale = 1.f, rs = 1.f;
    if (a > 0.f) {
      int e;
      float mant = frexpf(a, &e);
      int cc = (mant == 0.5f) ? (e - 1) : e;  // exact ceil(log2(amax))
      scale = ldexpf(1.f, cc - 3);
      rs = ldexpf(1.f, 3 - cc);
    }
    int d = d0 + nj * 16 + l15;
#pragma unroll
    for (int mi = 0; mi < 8; ++mi) {
      int m0 = mbase + wm * 128 + mi * 16 + lhi * 4;
      int b = m0 >> 11, s0 = m0 & 2047;
      uint2 pk;
      float v0 = quant1(acc[mi][nj][0], scale, rs);
      float v1 = quant1(acc[mi][nj][1], scale, rs);
      float v2 = quant1(acc[mi][nj][2], scale, rs);
      float v3 = quant1(acc[mi][nj][3], scale, rs);
      pk.x = (u32)f2b(v0) | ((u32)f2b(v1) << 16);
      pk.y = (u32)f2b(v2) | ((u32)f2b(v3) << 16);
      *(uint2*)(vt + ((size_t)(b * 32 + h) * 128 + d) * 2048 + s0) = pk;
    }
  }
}

// ======== FALLBACK PATH (used when ws_size is small) ========
template <int EPI>
__global__ __launch_bounds__(256) void k_gemm(const u16* __restrict__ A,
                                              const float* __restrict__ B,
                                              void* __restrict__ outp,
                                              const float* __restrict__ cost,
                                              const float* __restrict__ sint) {
  __shared__ u16 As[128 * 64];
  __shared__ u16 Bs[128 * 64];
  const int tid = threadIdx.x;
  const int w = tid >> 6, lane = tid & 63;
  const int l15 = lane & 15, lhi = lane >> 4;
  const int mbase = blockIdx.y * 128, nbase = blockIdx.x * 128;
  f32x4 acc[2][8];
#pragma unroll
  for (int i = 0; i < 2; ++i)
#pragma unroll
    for (int j = 0; j < 8; ++j) acc[i][j] = (f32x4){0.f, 0.f, 0.f, 0.f};

  const int brow = tid >> 1, bk = (tid & 1) * 32;
  const float* bsrc = B + (size_t)(nbase + brow) * 4096 + bk;

  for (int kt = 0; kt < 64; ++kt) {
    const int k0 = kt * 64;
#pragma unroll
    for (int i = 0; i < 4; ++i) {
      int idx = i * 256 + tid;
      int row = idx >> 3;
      int inb = ((idx & 7) << 4) ^ ((row & 7) << 4);
      gload16(A + (size_t)(mbase + row) * 4096 + (k0 + (inb >> 1)), (char*)As + idx * 16);
    }
    float4 bv[8];
    const float* bp = bsrc + k0;
#pragma unroll
    for (int c = 0; c < 8; ++c) bv[c] = *(const float4*)(bp + c * 4);
#pragma unroll
    for (int c = 0; c < 4; ++c) {
      uint4 pk;
      pk.x = (u32)f2b(bv[2 * c].x) | ((u32)f2b(bv[2 * c].y) << 16);
      pk.y = (u32)f2b(bv[2 * c].z) | ((u32)f2b(bv[2 * c].w) << 16);
      pk.z = (u32)f2b(bv[2 * c + 1].x) | ((u32)f2b(bv[2 * c + 1].y) << 16);
      pk.w = (u32)f2b(bv[2 * c + 1].z) | ((u32)f2b(bv[2 * c + 1].w) << 16);
      int byte = brow * 128 + (((bk + c * 8) * 2) ^ ((brow & 7) << 4));
      *(uint4*)((char*)Bs + byte) = pk;
    }
    __syncthreads();
#pragma unroll
    for (int ks = 0; ks < 2; ++ks) {
      const int kk2 = (ks * 32 + lhi * 8) * 2;
      bf16x8 af[2], bfr[8];
#pragma unroll
      for (int i = 0; i < 2; ++i) {
        int row = w * 32 + i * 16 + l15;
        af[i] = *(const bf16x8*)((const char*)As + row * 128 + (kk2 ^ ((row & 7) << 4)));
      }
#pragma unroll
      for (int j = 0; j < 8; ++j) {
        int row = j * 16 + l15;
        bfr[j] = *(const bf16x8*)((const char*)Bs + row * 128 + (kk2 ^ ((row & 7) << 4)));
      }
#pragma unroll
      for (int i = 0; i < 2; ++i)
#pragma unroll
        for (int j = 0; j < 8; ++j) acc[i][j] = MFMA16(af[i], bfr[j], acc[i][j]);
    }
    __syncthreads();
  }

  const int h = nbase >> 7;
  if constexpr (EPI == 3) {
    float* out = (float*)outp;
#pragma unroll
    for (int i = 0; i < 2; ++i)
#pragma unroll
      for (int r = 0; r < 4; ++r) {
        size_t m = (size_t)(mbase + w * 32 + i * 16 + lhi * 4 + r);
#pragma unroll
        for (int j = 0; j < 8; ++j) out[m * 4096 + nbase + j * 16 + l15] = acc[i][j][r];
      }
  } else {
    u16* qo = (u16*)outp;
#pragma unroll
    for (int i = 0; i < 2; ++i)
#pragma unroll
      for (int r = 0; r < 4; ++r) {
        int m = mbase + w * 32 + i * 16 + lhi * 4 + r;
        int b = m >> 11, s = m & 2047;
        const float* ct = cost + (size_t)s * 64;
        const float* st = sint + (size_t)s * 64;
        size_t base = ((size_t)(b * 32 + h) * 2048 + s) * 128;
#pragma unroll
        for (int j = 0; j < 4; ++j) {
          int d = j * 16 + l15;
          float c = ct[d], sn = st[d];
          float x1 = acc[i][j][r], x2 = acc[i][j + 4][r];
          qo[base + d] = f2b(x1 * c - x2 * sn);
          qo[base + d + 64] = f2b(x2 * c + x1 * sn);
        }
      }
  }
}

__global__ __launch_bounds__(256) void k_gemmv(const float* __restrict__ hsf,
                                               const float* __restrict__ Wv,
                                               u16* __restrict__ vt) {
  __shared__ u16 AsHi[128 * 64];
  __shared__ u16 AsLo[128 * 64];
  __shared__ u16 BsHi[128 * 64];
  __shared__ u16 BsLo[128 * 64];
  const int tid = threadIdx.x;
  const int w = tid >> 6, lane = tid & 63;
  const int l15 = lane & 15, lhi = lane >> 4;
  const int mbase = blockIdx.y * 128, nbase = blockIdx.x * 128;
  f32x4 acc[2][8];
#pragma unroll
  for (int i = 0; i < 2; ++i)
#pragma unroll
    for (int j = 0; j < 8; ++j) acc[i][j] = (f32x4){0.f, 0.f, 0.f, 0.f};

  const int srow = tid >> 1, sk = (tid & 1) * 32;
  const float* asrc = hsf + (size_t)(mbase + srow) * 4096 + sk;
  const float* bsrc = Wv + (size_t)(nbase + srow) * 4096 + sk;

  for (int kt = 0; kt < 64; ++kt) {
    const int k0 = kt * 64;
    float4 av[8], bv[8];
#pragma unroll
    for (int c = 0; c < 8; ++c) {
      av[c] = *(const float4*)(asrc + k0 + c * 4);
      bv[c] = *(const float4*)(bsrc + k0 + c * 4);
    }
#pragma unroll
    for (int c = 0; c < 4; ++c) {
      u16 h0, l0, h1, l1;
      float fa[8] = {av[2 * c].x, av[2 * c].y, av[2 * c].z, av[2 * c].w,
                     av[2 * c + 1].x, av[2 * c + 1].y, av[2 * c + 1].z, av[2 * c + 1].w};
      float fb[8] = {bv[2 * c].x, bv[2 * c].y, bv[2 * c].z, bv[2 * c].w,
                     bv[2 * c + 1].x, bv[2 * c + 1].y, bv[2 * c + 1].z, bv[2 * c + 1].w};
      u32 ph[4], pl[4], qh[4], ql[4];
#pragma unroll
      for (int t = 0; t < 4; ++t) {
        split2(fa[2 * t], h0, l0);
        split2(fa[2 * t + 1], h1, l1);
        ph[t] = (u32)h0 | ((u32)h1 << 16);
        pl[t] = (u32)l0 | ((u32)l1 << 16);
        split2(fb[2 * t], h0, l0);
        split2(fb[2 * t + 1], h1, l1);
        qh[t] = (u32)h0 | ((u32)h1 << 16);
        ql[t] = (u32)l0 | ((u32)l1 << 16);
      }
      int byte = srow * 128 + (((sk + c * 8) * 2) ^ ((srow & 7) << 4));
      *(uint4*)((char*)AsHi + byte) = make_uint4(ph[0], ph[1], ph[2], ph[3]);
      *(uint4*)((char*)AsLo + byte) = make_uint4(pl[0], pl[1], pl[2], pl[3]);
      *(uint4*)((char*)BsHi + byte) = make_uint4(qh[0], qh[1], qh[2], qh[3]);
      *(uint4*)((char*)BsLo + byte) = make_uint4(ql[0], ql[1], ql[2], ql[3]);
    }
    __syncthreads();
#pragma unroll
    for (int ks = 0; ks < 2; ++ks) {
      const int kk2 = (ks * 32 + lhi * 8) * 2;
      bf16x8 afh[2], afl[2];
#pragma unroll
      for (int i = 0; i < 2; ++i) {
        int row = w * 32 + i * 16 + l15;
        int off = row * 128 + (kk2 ^ ((row & 7) << 4));
        afh[i] = *(const bf16x8*)((const char*)AsHi + off);
        afl[i] = *(const bf16x8*)((const char*)AsLo + off);
      }
#pragma unroll
      for (int j = 0; j < 8; ++j) {
        int row = j * 16 + l15;
        int off = row * 128 + (kk2 ^ ((row & 7) << 4));
        bf16x8 bh = *(const bf16x8*)((const char*)BsHi + off);
        bf16x8 bl = *(const bf16x8*)((const char*)BsLo + off);
#pragma unroll
        for (int i = 0; i < 2; ++i) {
          acc[i][j] = MFMA16(afh[i], bh, acc[i][j]);
          acc[i][j] = MFMA16(afh[i], bl, acc[i][j]);
          acc[i][j] = MFMA16(afl[i], bh, acc[i][j]);
        }
      }
    }
    __syncthreads();
  }

  const int h = nbase >> 7;
  float pam[8];
#pragma unroll
  for (int j = 0; j < 8; ++j) {
    float a = 0.f;
#pragma unroll
    for (int i = 0; i < 2; ++i)
#pragma unroll
      for (int r = 0; r < 4; ++r) a = fmaxf(a, fabsf(acc[i][j][r]));
    a = fmaxf(a, __shfl_xor(a, 16));
    a = fmaxf(a, __shfl_xor(a, 32));
    pam[j] = a;
  }
  float* red = (float*)BsHi;
  if (lhi == 0) {
#pragma unroll
    for (int j = 0; j < 8; ++j) red[w * 128 + j * 16 + l15] = pam[j];
  }
  __syncthreads();
#pragma unroll
  for (int j = 0; j < 8; ++j) {
    float amax = fmaxf(fmaxf(red[0 * 128 + j * 16 + l15], red[1 * 128 + j * 16 + l15]),
                       fmaxf(red[2 * 128 + j * 16 + l15], red[3 * 128 + j * 16 + l15]));
    float scale = 1.f, rs = 1.f;
    if (amax > 0.f) {
      int e;
      float mant = frexpf(amax, &e);
      int c = (mant == 0.5f) ? (e - 1) : e;
      scale = ldexpf(1.f, c - 3);
      rs = ldexpf(1.f, 3 - c);
    }
#pragma unroll
    for (int i = 0; i < 2; ++i) {
      int m0 = mbase + w * 32 + i * 16 + lhi * 4;
      int b = m0 >> 11, s0 = m0 & 2047;
      int d = j * 16 + l15;
      uint2 pk;
      float v0 = quant1(acc[i][j][0], scale, rs);
      float v1 = quant1(acc[i][j][1], scale, rs);
      float v2 = quant1(acc[i][j][2], scale, rs);
      float v3 = quant1(acc[i][j][3], scale, rs);
      pk.x = (u32)f2b(v0) | ((u32)f2b(v1) << 16);
      pk.y = (u32)f2b(v2) | ((u32)f2b(v3) << 16);
      *(uint2*)(vt + ((size_t)(b * 32 + h) * 128 + d) * 2048 + s0) = pk;
    }
  }
}

// ---------------- R11 flash attention (causal): QB=128 (8 waves), KB=64,
// swapped QK^T (mfma(K,Q)) -> softmax row is lane-local (q = l15):
// row-reduce = 2 shuffles, P-store = 4 x ds_write_b64. PV & staging unchanged.
__global__ __launch_bounds__(512, 4) void k_attn(const u16* __restrict__ qg,
                                                 const u16* __restrict__ kg,
                                                 const u16* __restrict__ vtg,
                                                 u16* __restrict__ ao) {
  __shared__ u16 Ks[2][64 * 128];  // 32KB: [kk][d], 256B rows, swizzled by ((row&15)<<4)
  __shared__ u16 Vs[2][128 * 64];  // 32KB: [d][s], 128B rows, swizzled by ((row&7)<<4)
  __shared__ u16 Ps[8 * 16 * 64];  // 16KB: per-wave P [16 q][64 k], byte ^= ((q&7)<<4)
  const int qt = 15 - blockIdx.y;  // longest blocks dispatch first
  const int bh = blockIdx.x;
  const int tid = threadIdx.x, w = tid >> 6, lane = tid & 63;
  const int l15 = lane & 15, lhi = lane >> 4;
  const size_t bhoff = (size_t)bh * (2048 * 128);
  const float SC = 0.08838834764831845f;  // 1/sqrt(128)

  bf16x8 qf[4];
  {
    const int qrow = qt * 128 + w * 16 + l15;
    const u16* qp = qg + bhoff + (size_t)qrow * 128 + lhi * 8;
#pragma unroll
    for (int ks = 0; ks < 4; ++ks) qf[ks] = *(const bf16x8*)(qp + ks * 32);
  }
  f32x4 oacc[8];
#pragma unroll
  for (int dt = 0; dt < 8; ++dt) oacc[dt] = (f32x4){0.f, 0.f, 0.f, 0.f};
  float mr = -1e30f, lr = 0.f;  // online-softmax state for q = w*16 + l15 (lane-local)

  auto stage = [&](int buf, int kbase) {
#pragma unroll
    for (int i = 0; i < 2; ++i) {
      int idx = i * 512 + tid;
      int row = idx >> 4;
      int inb = ((idx & 15) << 4) ^ ((row & 15) << 4);
      gload16(kg + bhoff + (size_t)(kbase + row) * 128 + (inb >> 1), (char*)Ks[buf] + idx * 16);
    }
#pragma unroll
    for (int i = 0; i < 2; ++i) {
      int idx = i * 512 + tid;
      int row = idx >> 3;
      int inb = ((idx & 7) << 4) ^ ((row & 7) << 4);
      gload16(vtg + bhoff + (size_t)row * 2048 + kbase + (inb >> 1), (char*)Vs[buf] + idx * 16);
    }
  };

  const int nt = 2 * qt + 2;
  stage(0, 0);

  for (int kt = 0; kt < nt; ++kt) {
    const int cur = kt & 1;
    if (kt < nt - 1) {
      stage(cur ^ 1, (kt + 1) * 64);
      asm volatile("s_waitcnt vmcnt(4)" ::: "memory");
    } else {
      asm volatile("s_waitcnt vmcnt(0)" ::: "memory");
    }
    __builtin_amdgcn_s_barrier();

    // swapped QK^T: mfma(K, Q) -> C[m=k][n=q]; lane: q = l15, k = j*16 + lhi*4 + r
    f32x4 sc4[4];
#pragma unroll
    for (int j = 0; j < 4; ++j) sc4[j] = (f32x4){0.f, 0.f, 0.f, 0.f};
    __builtin_amdgcn_s_setprio(1);
#pragma unroll
    for (int ks = 0; ks < 4; ++ks) {
      const int db = (ks * 32 + lhi * 8) * 2;
#pragma unroll
      for (int j = 0; j < 4; ++j) {
        int kr = j * 16 + l15;
        bf16x8 bfr = *(const bf16x8*)((const char*)Ks[cur] + kr * 256 + (db ^ ((kr & 15) << 4)));
        sc4[j] = MFMA16(bfr, qf[ks], sc4[j]);
      }
    }
    __builtin_amdgcn_s_setprio(0);
    float p[4][4];
    const int kbase = kt * 64;
    const bool tail = (kt >= 2 * qt);
    const int qrow = qt * 128 + w * 16 + l15;
#pragma unroll
    for (int j = 0; j < 4; ++j)
#pragma unroll
      for (int r = 0; r < 4; ++r) {
        float s = sc4[j][r] * SC;
        if (tail && (kbase + j * 16 + lhi * 4 + r > qrow)) s = -1e9f;
        p[j][r] = s;
      }
    // lane-local softmax for q = l15's row (16 values) + 2-shuffle cross-group reduce
    float tm = -1e30f;
#pragma unroll
    for (int j = 0; j < 4; ++j)
#pragma unroll
      for (int r = 0; r < 4; ++r) tm = fmaxf(tm, p[j][r]);
    tm = fmaxf(tm, __shfl_xor(tm, 16));
    tm = fmaxf(tm, __shfl_xor(tm, 32));
    float mn = fmaxf(mr, tm);
    float alpha = __expf(mr - mn);
    mr = mn;
    float rsum = 0.f;
#pragma unroll
    for (int j = 0; j < 4; ++j)
#pragma unroll
      for (int r = 0; r < 4; ++r) {
        float e = __expf(p[j][r] - mn);
        p[j][r] = e;
        rsum += e;
      }
    rsum += __shfl_xor(rsum, 16);
    rsum += __shfl_xor(rsum, 32);
    lr = lr * alpha + rsum;
    // redistribute alpha to oacc rows (q = w*16 + lhi*4 + r lives at lane l15' = lhi*4+r)
    float aq[4];
#pragma unroll
    for (int r = 0; r < 4; ++r) aq[r] = __shfl(alpha, (lane & 48) | (lhi * 4 + r));
#pragma unroll
    for (int dt = 0; dt < 8; ++dt) {
      f32x4 t = oacc[dt];
      t[0] *= aq[0]; t[1] *= aq[1]; t[2] *= aq[2]; t[3] *= aq[3];
      oacc[dt] = t;
    }
    // P -> per-wave LDS [16 q][64 k]: per j, 4 consecutive k -> one ds_write_b64
#pragma unroll
    for (int j = 0; j < 4; ++j) {
      u32 lo = (u32)f2b(p[j][0]) | ((u32)f2b(p[j][1]) << 16);
      u32 hi = (u32)f2b(p[j][2]) | ((u32)f2b(p[j][3]) << 16);
      int byte = w * 2048 + l15 * 128 + (((j * 16 + lhi * 4) * 2) ^ ((l15 & 7) << 4));
      *(uint2*)((char*)Ps + byte) = make_uint2(lo, hi);
    }
    __builtin_amdgcn_s_setprio(1);
#pragma unroll
    for (int ks2 = 0; ks2 < 2; ++ks2) {
      const int sb = ks2 * 32 + lhi * 8;
      bf16x8 pa = *(const bf16x8*)((const char*)Ps + w * 2048 + l15 * 128 +
                                   ((sb * 2) ^ ((l15 & 7) << 4)));
#pragma unroll
      for (int dt = 0; dt < 8; ++dt) {
        int d = dt * 16 + l15;
        bf16x8 vb = *(const bf16x8*)((const char*)Vs[cur] + d * 128 + ((sb * 2) ^ ((d & 7) << 4)));
        oacc[dt] = MFMA16(pa, vb, oacc[dt]);
      }
    }
    __builtin_amdgcn_s_setprio(0);
    asm volatile("s_waitcnt lgkmcnt(0)" ::: "memory");
    __builtin_amdgcn_s_barrier();
  }

  const int b = bh >> 5, h = bh & 31;
  float linv = 1.f / lr;  // for q = l15
  float inv[4];
#pragma unroll
  for (int r = 0; r < 4; ++r) inv[r] = __shfl(linv, (lane & 48) | (lhi * 4 + r));
#pragma unroll
  for (int dt = 0; dt < 8; ++dt)
#pragma unroll
    for (int r = 0; r < 4; ++r) {
      int s = qt * 128 + w * 16 + lhi * 4 + r;
      ao[((size_t)(b * 2048 + s)) * 4096 + h * 128 + dt * 16 + l15] = f2b(oacc[dt][r] * inv[r]);
    }
}

extern "C" void kernel_launch(void* const* d_in, const int* in_sizes, int n_in,
                              void* d_out, int out_size, void* d_ws, size_t ws_size,
                              hipStream_t stream) {
  (void)in_sizes; (void)n_in; (void)out_size;
  const float* hs = (const float*)d_in[0];
  const int* pid = (const int*)d_in[1];
  const float* Wq = (const float*)d_in[2];
  const float* Wk = (const float*)d_in[3];
  const float* Wv = (const float*)d_in[4];
  const float* Wo = (const float*)d_in[5];
  float* out = (float*)d_out;
  char* ws = (char*)d_ws;

  const size_t BUF = 33554432;  // one 4096x4096 bf16 buffer
  const size_t NEED = 7 * BUF + 2 * 524288;

  if (ws_size >= NEED) {
    u16* hsb  = (u16*)(ws + 0 * BUF);          // hs hi
    u16* hslo = (u16*)(ws + 1 * BUF);          // hs lo; later aob
    u16* qb   = (u16*)(ws + 2 * BUF);
    u16* kb   = (u16*)(ws + 3 * BUF);
    u16* vtb  = (u16*)(ws + 4 * BUF);
    u16* wbuf = (u16*)(ws + 5 * BUF);          // Wq_b -> Wk_b -> Wv_hi -> Wo_b (sequential)
    u16* wvlo = (u16*)(ws + 6 * BUF);
    float* cost = (float*)(ws + 7 * BUF);
    float* sint = (float*)(ws + 7 * BUF + 524288);
    u16* aob = hslo;

    k_splt<<<16384, 256, 0, stream>>>(hs, hsb, hslo);
    k_rope_tab<<<512, 256, 0, stream>>>(pid, cost, sint);
    k_cvt<<<16384, 256, 0, stream>>>(Wq, wbuf);
    k_gemm8<0><<<256, 512, 0, stream>>>(hsb, wbuf, (void*)qb, cost, sint);
    k_cvt<<<16384, 256, 0, stream>>>(Wk, wbuf);
    k_gemm8<1><<<256, 512, 0, stream>>>(hsb, wbuf, (void*)kb, cost, sint);
    k_splt<<<16384, 256, 0, stream>>>(Wv, wbuf, wvlo);
    k_gemmv4<<<256, 512, 0, stream>>>(hsb, hslo, wbuf, wvlo, vtb);
    k_attn<<<dim3(64, 16), 512, 0, stream>>>(qb, kb, vtb, aob);
    k_cvt<<<16384, 256, 0, stream>>>(Wo, wbuf);
    k_gemm8<3><<<256, 512, 0, stream>>>(aob, wbuf, (void*)out, nullptr, nullptr);
  } else {
    u16* hsb = (u16*)(ws + 0);
    u16* qb  = (u16*)(ws + 33554432);
    u16* kb  = (u16*)(ws + 67108864);
    u16* vtb = (u16*)(ws + 100663296);
    float* cost = (float*)(ws + 134217728);
    float* sint = (float*)(ws + 134742016);
    u16* aob = hsb;

    k_cvt<<<16384, 256, 0, stream>>>(hs, hsb);
    k_rope_tab<<<512, 256, 0, stream>>>(pid, cost, sint);
    k_gemm<0><<<dim3(32, 32), 256, 0, stream>>>(hsb, Wq, (void*)qb, cost, sint);
    k_gemm<1><<<dim3(32, 32), 256, 0, stream>>>(hsb, Wk, (void*)kb, cost, sint);
    k_gemmv<<<dim3(32, 32), 256, 0, stream>>>(hs, Wv, vtb);
    k_attn<<<dim3(64, 16), 512, 0, stream>>>(qb, kb, vtb, aob);
    k_gemm<3><<<dim3(32, 32), 256, 0, stream>>>(aob, Wo, (void*)out, nullptr, nullptr);
  }
}

// Round 12
// 842.093 us; speedup vs baseline: 1.0953x; 1.0050x over previous
//
#include <hip/hip_runtime.h>
#include <math.h>

typedef unsigned short u16;
typedef unsigned int u32;
typedef short bf16x8 __attribute__((ext_vector_type(8)));
typedef float f32x4 __attribute__((ext_vector_type(4)));

#define MFMA16(a, b, c) __builtin_amdgcn_mfma_f32_16x16x32_bf16(a, b, c, 0, 0, 0)

static __device__ __forceinline__ u16 f2b(float f) {
  u32 u = __builtin_bit_cast(u32, f);
  u = (u + 0x7fffu + ((u >> 16) & 1u)) >> 16;
  return (u16)u;
}
static __device__ __forceinline__ float b2f(u16 h) {
  return __builtin_bit_cast(float, ((u32)h) << 16);
}
static __device__ __forceinline__ void gload16(const void* g, void* l) {
  __builtin_amdgcn_global_load_lds((const __attribute__((address_space(1))) void*)g,
                                   (__attribute__((address_space(3))) void*)l, 16, 0, 0);
}
// split f32 into hi-bf16 + lo-bf16 (x ~= hi + lo, rel err ~2^-18)
static __device__ __forceinline__ void split2(float x, u16& hi, u16& lo) {
  hi = f2b(x);
  lo = f2b(x - b2f(hi));
}
static __device__ __forceinline__ float quant1(float x, float scale, float rs) {
  float y = fabsf(x) * rs;
  float st = y < 2.f ? 0.5f : (y < 4.f ? 1.f : 2.f);
  float iv = y < 2.f ? 2.f : (y < 4.f ? 1.f : 0.5f);
  float q = fminf(rintf(y * iv) * st, 6.f);  // rintf = RNE = jnp.round
  return copysignf(q * scale, x);
}

// ---------------- f32 -> bf16 convert ----------------
__global__ __launch_bounds__(256) void k_cvt(const float* __restrict__ in, u16* __restrict__ out) {
  int i = blockIdx.x * 256 + threadIdx.x;
  float4 v = ((const float4*)in)[i];
  u32 lo = (u32)f2b(v.x) | ((u32)f2b(v.y) << 16);
  u32 hi = (u32)f2b(v.z) | ((u32)f2b(v.w) << 16);
  ((uint2*)out)[i] = make_uint2(lo, hi);
}

// ---------------- f32 -> (hi,lo) bf16 split ----------------
__global__ __launch_bounds__(256) void k_splt(const float* __restrict__ in,
                                              u16* __restrict__ hi, u16* __restrict__ lo) {
  int i = blockIdx.x * 256 + threadIdx.x;
  float4 v = ((const float4*)in)[i];
  u16 h[4], l[4];
  split2(v.x, h[0], l[0]);
  split2(v.y, h[1], l[1]);
  split2(v.z, h[2], l[2]);
  split2(v.w, h[3], l[3]);
  ((uint2*)hi)[i] = make_uint2((u32)h[0] | ((u32)h[1] << 16), (u32)h[2] | ((u32)h[3] << 16));
  ((uint2*)lo)[i] = make_uint2((u32)l[0] | ((u32)l[1] << 16), (u32)l[2] | ((u32)l[3] << 16));
}

// ---------------- rope tables: [2048][64] cos & sin ----------------
__global__ __launch_bounds__(256) void k_rope_tab(const int* __restrict__ pid,
                                                  float* __restrict__ ct,
                                                  float* __restrict__ st) {
  int t = blockIdx.x * 256 + threadIdx.x;  // 131072 total
  int s = t >> 6, i = t & 63;
  float inv = powf(10000.f, -(float)i * (1.f / 64.f));
  float a = (float)pid[s] * inv;
  ct[t] = cosf(a);
  st[t] = sinf(a);
}

// ======== 256x256 8-phase bf16 GEMM (T2+T3+T4+T5), both operands gload_lds ========
// C[4096][4096] = A(bf16,[M][K]) * B(bf16,[N][K])^T, BK=64, 8 waves.
// EPI 0/1: rope -> (b,h,s,d) bf16 ; EPI 3: f32 -> d_out.
template <int EPI>
__global__ __launch_bounds__(512, 2) void k_gemm8(const u16* __restrict__ A,
                                                  const u16* __restrict__ B,
                                                  void* __restrict__ outp,
                                                  const float* __restrict__ cost,
                                                  const float* __restrict__ sint) {
  __shared__ u16 Ls[2][2][2][8192];  // [buf][A=0/B=1][half][128*64], 16KB each, 128KB total
  const int tid = threadIdx.x;
  const int wid = tid >> 6, lane = tid & 63;
  const int l15 = lane & 15, lhi = lane >> 4;
  const int wm = wid >> 2, wn = wid & 3;
  const int hib = wn >> 1, sub = wn & 1;

  const int bid = blockIdx.x;
  const int bx = 2 * (bid & 7) + (bid >> 7);   // N-block 0..15
  const int by = (bid >> 3) & 15;              // M-block 0..15
  const int mbase = by * 256, nbase = bx * 256;

  f32x4 acc[8][4];
#pragma unroll
  for (int mi = 0; mi < 8; ++mi)
#pragma unroll
    for (int nj = 0; nj < 4; ++nj) acc[mi][nj] = (f32x4){0.f, 0.f, 0.f, 0.f};

  auto stA = [&](int buf, int half, int ktile) {
    u16* dst = Ls[buf][0][half];
    const int k0 = ktile * 64;
#pragma unroll
    for (int i = 0; i < 2; ++i) {
      int idx = i * 512 + tid;
      int row = idx >> 3;
      int col = k0 + ((((idx & 7) << 4) ^ ((row & 7) << 4)) >> 1);
      gload16(A + (size_t)(mbase + half * 128 + row) * 4096 + col, (char*)dst + idx * 16);
    }
  };
  auto stB = [&](int buf, int half, int ktile) {
    u16* dst = Ls[buf][1][half];
    const int k0 = ktile * 64;
#pragma unroll
    for (int i = 0; i < 2; ++i) {
      int idx = i * 512 + tid;
      int row = idx >> 3;
      int col = k0 + ((((idx & 7) << 4) ^ ((row & 7) << 4)) >> 1);
      gload16(B + (size_t)(nbase + half * 128 + row) * 4096 + col, (char*)dst + idx * 16);
    }
  };

  stB(0, 0, 0);
  stB(0, 1, 0);
  stA(0, 0, 0);
  stA(0, 1, 0);
  stB(1, 0, 1);
  stB(1, 1, 1);

  const int NT = 64;
  for (int kt = 0; kt < NT; ++kt) {
    const int cur = kt & 1, nxt = cur ^ 1;
    const u16* Ab = Ls[cur][0][wm];
    const u16* Bb = Ls[cur][1][hib];
    bf16x8 aA[4][2], aB[4][2], bA[2][2], bB[2][2];

    // ---- phase 0 ----
    if (kt + 1 < NT) stA(nxt, 0, kt + 1);
    if (kt == NT - 1) {
      asm volatile("s_waitcnt vmcnt(0)" ::: "memory");
    } else {
      asm volatile("s_waitcnt vmcnt(6)" ::: "memory");
    }
    __builtin_amdgcn_s_barrier();
#pragma unroll
    for (int mi = 0; mi < 4; ++mi)
#pragma unroll
      for (int ks = 0; ks < 2; ++ks) {
        int row = mi * 16 + l15;
        int kk2 = (ks * 32 + lhi * 8) * 2;
        aA[mi][ks] = *(const bf16x8*)((const char*)Ab + row * 128 + (kk2 ^ ((row & 7) << 4)));
      }
#pragma unroll
    for (int nj = 0; nj < 2; ++nj)
#pragma unroll
      for (int ks = 0; ks < 2; ++ks) {
        int row = sub * 32 + nj * 16 + l15;
        int kk2 = (ks * 32 + lhi * 8) * 2;
        bA[nj][ks] = *(const bf16x8*)((const char*)Bb + row * 128 + (kk2 ^ ((row & 7) << 4)));
      }
    __builtin_amdgcn_s_setprio(1);
#pragma unroll
    for (int mi = 0; mi < 4; ++mi)
#pragma unroll
      for (int nj = 0; nj < 2; ++nj)
#pragma unroll
        for (int ks = 0; ks < 2; ++ks) acc[mi][nj] = MFMA16(aA[mi][ks], bA[nj][ks], acc[mi][nj]);
    __builtin_amdgcn_s_setprio(0);
    __builtin_amdgcn_s_barrier();

    // ---- phase 1 ----
#pragma unroll
    for (int nj = 0; nj < 2; ++nj)
#pragma unroll
      for (int ks = 0; ks < 2; ++ks) {
        int row = 64 + sub * 32 + nj * 16 + l15;
        int kk2 = (ks * 32 + lhi * 8) * 2;
        bB[nj][ks] = *(const bf16x8*)((const char*)Bb + row * 128 + (kk2 ^ ((row & 7) << 4)));
      }
    if (kt + 1 < NT) stA(nxt, 1, kt + 1);
    __builtin_amdgcn_s_barrier();
    __builtin_amdgcn_s_setprio(1);
#pragma unroll
    for (int mi = 0; mi < 4; ++mi)
#pragma unroll
      for (int nj = 0; nj < 2; ++nj)
#pragma unroll
        for (int ks = 0; ks < 2; ++ks)
          acc[mi][nj + 2] = MFMA16(aA[mi][ks], bB[nj][ks], acc[mi][nj + 2]);
    __builtin_amdgcn_s_setprio(0);
    __builtin_amdgcn_s_barrier();

    // ---- phase 2 ----
#pragma unroll
    for (int mi = 0; mi < 4; ++mi)
#pragma unroll
      for (int ks = 0; ks < 2; ++ks) {
        int row = 64 + mi * 16 + l15;
        int kk2 = (ks * 32 + lhi * 8) * 2;
        aB[mi][ks] = *(const bf16x8*)((const char*)Ab + row * 128 + (kk2 ^ ((row & 7) << 4)));
      }
    if (kt + 2 < NT) stB(cur, 0, kt + 2);
    __builtin_amdgcn_s_barrier();
    __builtin_amdgcn_s_setprio(1);
#pragma unroll
    for (int mi = 0; mi < 4; ++mi)
#pragma unroll
      for (int nj = 0; nj < 2; ++nj)
#pragma unroll
        for (int ks = 0; ks < 2; ++ks)
          acc[mi + 4][nj] = MFMA16(aB[mi][ks], bA[nj][ks], acc[mi + 4][nj]);
    __builtin_amdgcn_s_setprio(0);
    __builtin_amdgcn_s_barrier();

    // ---- phase 3 ----
    if (kt + 2 < NT) stB(cur, 1, kt + 2);
    __builtin_amdgcn_s_barrier();
    __builtin_amdgcn_s_setprio(1);
#pragma unroll
    for (int mi = 0; mi < 4; ++mi)
#pragma unroll
      for (int nj = 0; nj < 2; ++nj)
#pragma unroll
        for (int ks = 0; ks < 2; ++ks)
          acc[mi + 4][nj + 2] = MFMA16(aB[mi][ks], bB[nj][ks], acc[mi + 4][nj + 2]);
    __builtin_amdgcn_s_setprio(0);
    __builtin_amdgcn_s_barrier();
  }

  if constexpr (EPI == 3) {
    float* out = (float*)outp;
#pragma unroll
    for (int mi = 0; mi < 8; ++mi)
#pragma unroll
      for (int r = 0; r < 4; ++r) {
        size_t m = (size_t)(mbase + wm * 128 + mi * 16 + lhi * 4 + r);
#pragma unroll
        for (int nj = 0; nj < 4; ++nj) {
          int n = nbase + hib * 128 + (nj >> 1) * 64 + sub * 32 + (nj & 1) * 16 + l15;
          out[m * 4096 + n] = acc[mi][nj][r];
        }
      }
  } else {
    u16* qo = (u16*)outp;
    const int hgl = bx * 2 + hib;
#pragma unroll
    for (int mi = 0; mi < 8; ++mi)
#pragma unroll
      for (int r = 0; r < 4; ++r) {
        int m = mbase + wm * 128 + mi * 16 + lhi * 4 + r;
        int b = m >> 11, s = m & 2047;
        const float* ct = cost + (size_t)s * 64;
        const float* st = sint + (size_t)s * 64;
        size_t base = ((size_t)(b * 32 + hgl) * 2048 + s) * 128;
#pragma unroll
        for (int nj = 0; nj < 2; ++nj) {
          int d = sub * 32 + nj * 16 + l15;
          float c = ct[d], sn = st[d];
          float x1 = acc[mi][nj][r], x2 = acc[mi][nj + 2][r];
          qo[base + d] = f2b(x1 * c - x2 * sn);
          qo[base + d + 64] = f2b(x2 * c + x1 * sn);
        }
      }
  }
}

// ======== V GEMM, 256² tile / BK=32 / 4-phase quadrant schedule (gemm8 clone),
// split-bf16 (Ahi,Alo,Bhi,Blo staged), fused MXFP4 quant. 8 waves, 128KB LDS.
__global__ __launch_bounds__(512, 2) void k_gemmv4(const u16* __restrict__ ahi,
                                                   const u16* __restrict__ alo,
                                                   const u16* __restrict__ bhi,
                                                   const u16* __restrict__ blo,
                                                   u16* __restrict__ vt) {
  __shared__ u16 Ls[2][4][256 * 32];  // [buf][Ahi,Alo,Bhi,Blo][256 rows][32 k], 16KB each
  const int tid = threadIdx.x;
  const int wid = tid >> 6, lane = tid & 63;
  const int l15 = lane & 15, lhi = lane >> 4;
  const int wm = wid >> 2, wn = wid & 3;  // wm: 128-row half (quant block), wn: 64-col quarter
  const int bid = blockIdx.x;
  const int bx = 2 * (bid & 7) + (bid >> 7);
  const int by = (bid >> 3) & 15;
  const int mbase = by * 256, nbase = bx * 256;

  f32x4 acc[8][4];
#pragma unroll
  for (int mi = 0; mi < 8; ++mi)
#pragma unroll
    for (int nj = 0; nj < 4; ++nj) acc[mi][nj] = (f32x4){0.f, 0.f, 0.f, 0.f};

  auto stg = [&](int buf, int mat, int ktile, const u16* src, int rbase) {
    const int k0 = ktile * 32;
#pragma unroll
    for (int i = 0; i < 2; ++i) {
      int idx = i * 512 + tid;  // 0..1023 16B chunks
      int row = idx >> 2, slot = idx & 3;
      int sslot = slot ^ ((row >> 1) & 3);
      gload16(src + (size_t)(rbase + row) * 4096 + k0 + sslot * 8,
              (char*)Ls[buf][mat] + idx * 16);
    }
  };
  auto rd = [&](const u16* base, int row) -> bf16x8 {
    return *(const bf16x8*)((const char*)base + row * 64 + ((lhi ^ ((row >> 1) & 3)) << 4));
  };

  stg(0, 0, 0, ahi, mbase);
  stg(0, 1, 0, alo, mbase);
  stg(0, 2, 0, bhi, nbase);
  stg(0, 3, 0, blo, nbase);
  stg(1, 2, 1, bhi, nbase);
  stg(1, 3, 1, blo, nbase);

  const int NT = 128;
  for (int kt = 0; kt < NT; ++kt) {
    const int cur = kt & 1, nxt = cur ^ 1;
    const u16* AH = Ls[cur][0];
    const u16* AL = Ls[cur][1];
    const u16* BH = Ls[cur][2];
    const u16* BL = Ls[cur][3];
    bf16x8 axh[4], axl[4], ayh[4], ayl[4], bxh[2], bxl[2], byh[2], byl[2];

    // ---- phase 0 ----
    if (kt + 1 < NT) stg(nxt, 0, kt + 1, ahi, mbase);
    if (kt == NT - 1) {
      asm volatile("s_waitcnt vmcnt(0)" ::: "memory");
    } else {
      asm volatile("s_waitcnt vmcnt(6)" ::: "memory");
    }
    __builtin_amdgcn_s_barrier();
#pragma unroll
    for (int mi = 0; mi < 4; ++mi) {
      int row = wm * 128 + mi * 16 + l15;
      axh[mi] = rd(AH, row);
      axl[mi] = rd(AL, row);
    }
#pragma unroll
    for (int nj = 0; nj < 2; ++nj) {
      int row = wn * 64 + nj * 16 + l15;
      bxh[nj] = rd(BH, row);
      bxl[nj] = rd(BL, row);
    }
    __builtin_amdgcn_s_setprio(1);
#pragma unroll
    for (int mi = 0; mi < 4; ++mi)
#pragma unroll
      for (int nj = 0; nj < 2; ++nj) {
        acc[mi][nj] = MFMA16(axh[mi], bxh[nj], acc[mi][nj]);
        acc[mi][nj] = MFMA16(axh[mi], bxl[nj], acc[mi][nj]);
        acc[mi][nj] = MFMA16(axl[mi], bxh[nj], acc[mi][nj]);
      }
    __builtin_amdgcn_s_setprio(0);
    __builtin_amdgcn_s_barrier();

    // ---- phase 1 ----
#pragma unroll
    for (int nj = 0; nj < 2; ++nj) {
      int row = wn * 64 + 32 + nj * 16 + l15;
      byh[nj] = rd(BH, row);
      byl[nj] = rd(BL, row);
    }
    if (kt + 1 < NT) stg(nxt, 1, kt + 1, alo, mbase);
    __builtin_amdgcn_s_barrier();
    __builtin_amdgcn_s_setprio(1);
#pragma unroll
    for (int mi = 0; mi < 4; ++mi)
#pragma unroll
      for (int nj = 0; nj < 2; ++nj) {
        acc[mi][nj + 2] = MFMA16(axh[mi], byh[nj], acc[mi][nj + 2]);
        acc[mi][nj + 2] = MFMA16(axh[mi], byl[nj], acc[mi][nj + 2]);
        acc[mi][nj + 2] = MFMA16(axl[mi], byh[nj], acc[mi][nj + 2]);
      }
    __builtin_amdgcn_s_setprio(0);
    __builtin_amdgcn_s_barrier();

    // ---- phase 2 ----
#pragma unroll
    for (int mi = 0; mi < 4; ++mi) {
      int row = wm * 128 + 64 + mi * 16 + l15;
      ayh[mi] = rd(AH, row);
      ayl[mi] = rd(AL, row);
    }
    if (kt + 2 < NT) stg(cur, 2, kt + 2, bhi, nbase);
    __builtin_amdgcn_s_barrier();
    __builtin_amdgcn_s_setprio(1);
#pragma unroll
    for (int mi = 0; mi < 4; ++mi)
#pragma unroll
      for (int nj = 0; nj < 2; ++nj) {
        acc[mi + 4][nj] = MFMA16(ayh[mi], bxh[nj], acc[mi + 4][nj]);
        acc[mi + 4][nj] = MFMA16(ayh[mi], bxl[nj], acc[mi + 4][nj]);
        acc[mi + 4][nj] = MFMA16(ayl[mi], bxh[nj], acc[mi + 4][nj]);
      }
    __builtin_amdgcn_s_setprio(0);
    __builtin_amdgcn_s_barrier();

    // ---- phase 3 ----
    if (kt + 2 < NT) stg(cur, 3, kt + 2, blo, nbase);
    __builtin_amdgcn_s_barrier();
    __builtin_amdgcn_s_setprio(1);
#pragma unroll
    for (int mi = 0; mi < 4; ++mi)
#pragma unroll
      for (int nj = 0; nj < 2; ++nj) {
        acc[mi + 4][nj + 2] = MFMA16(ayh[mi], byh[nj], acc[mi + 4][nj + 2]);
        acc[mi + 4][nj + 2] = MFMA16(ayh[mi], byl[nj], acc[mi + 4][nj + 2]);
        acc[mi + 4][nj + 2] = MFMA16(ayl[mi], byh[nj], acc[mi + 4][nj + 2]);
      }
    __builtin_amdgcn_s_setprio(0);
    __builtin_amdgcn_s_barrier();
  }

  // ---- fused MXFP4 quant: wave's 128 rows == exactly one quant block -> wave-local amax ----
  const int h = (nbase >> 7) + (wn >> 1);
  const int d0 = (wn & 1) * 64;
#pragma unroll
  for (int nj = 0; nj < 4; ++nj) {
    float a = 0.f;
#pragma unroll
    for (int mi = 0; mi < 8; ++mi)
#pragma unroll
      for (int r = 0; r < 4; ++r) a = fmaxf(a, fabsf(acc[mi][nj][r]));
    a = fmaxf(a, __shfl_xor(a, 16));
    a = fmaxf(a, __shfl_xor(a, 32));
    float scale = 1.f, rs = 1.f;
    if (a > 0.f) {
      int e;
      float mant = frexpf(a, &e);
      int cc = (mant == 0.5f) ? (e - 1) : e;  // exact ceil(log2(amax))
      scale = ldexpf(1.f, cc - 3);
      rs = ldexpf(1.f, 3 - cc);
    }
    int d = d0 + nj * 16 + l15;
#pragma unroll
    for (int mi = 0; mi < 8; ++mi) {
      int m0 = mbase + wm * 128 + mi * 16 + lhi * 4;
      int b = m0 >> 11, s0 = m0 & 2047;
      uint2 pk;
      float v0 = quant1(acc[mi][nj][0], scale, rs);
      float v1 = quant1(acc[mi][nj][1], scale, rs);
      float v2 = quant1(acc[mi][nj][2], scale, rs);
      float v3 = quant1(acc[mi][nj][3], scale, rs);
      pk.x = (u32)f2b(v0) | ((u32)f2b(v1) << 16);
      pk.y = (u32)f2b(v2) | ((u32)f2b(v3) << 16);
      *(uint2*)(vt + ((size_t)(b * 32 + h) * 128 + d) * 2048 + s0) = pk;
    }
  }
}

// ======== FALLBACK PATH (used when ws_size is small) ========
template <int EPI>
__global__ __launch_bounds__(256) void k_gemm(const u16* __restrict__ A,
                                              const float* __restrict__ B,
                                              void* __restrict__ outp,
                                              const float* __restrict__ cost,
                                              const float* __restrict__ sint) {
  __shared__ u16 As[128 * 64];
  __shared__ u16 Bs[128 * 64];
  const int tid = threadIdx.x;
  const int w = tid >> 6, lane = tid & 63;
  const int l15 = lane & 15, lhi = lane >> 4;
  const int mbase = blockIdx.y * 128, nbase = blockIdx.x * 128;
  f32x4 acc[2][8];
#pragma unroll
  for (int i = 0; i < 2; ++i)
#pragma unroll
    for (int j = 0; j < 8; ++j) acc[i][j] = (f32x4){0.f, 0.f, 0.f, 0.f};

  const int brow = tid >> 1, bk = (tid & 1) * 32;
  const float* bsrc = B + (size_t)(nbase + brow) * 4096 + bk;

  for (int kt = 0; kt < 64; ++kt) {
    const int k0 = kt * 64;
#pragma unroll
    for (int i = 0; i < 4; ++i) {
      int idx = i * 256 + tid;
      int row = idx >> 3;
      int inb = ((idx & 7) << 4) ^ ((row & 7) << 4);
      gload16(A + (size_t)(mbase + row) * 4096 + (k0 + (inb >> 1)), (char*)As + idx * 16);
    }
    float4 bv[8];
    const float* bp = bsrc + k0;
#pragma unroll
    for (int c = 0; c < 8; ++c) bv[c] = *(const float4*)(bp + c * 4);
#pragma unroll
    for (int c = 0; c < 4; ++c) {
      uint4 pk;
      pk.x = (u32)f2b(bv[2 * c].x) | ((u32)f2b(bv[2 * c].y) << 16);
      pk.y = (u32)f2b(bv[2 * c].z) | ((u32)f2b(bv[2 * c].w) << 16);
      pk.z = (u32)f2b(bv[2 * c + 1].x) | ((u32)f2b(bv[2 * c + 1].y) << 16);
      pk.w = (u32)f2b(bv[2 * c + 1].z) | ((u32)f2b(bv[2 * c + 1].w) << 16);
      int byte = brow * 128 + (((bk + c * 8) * 2) ^ ((brow & 7) << 4));
      *(uint4*)((char*)Bs + byte) = pk;
    }
    __syncthreads();
#pragma unroll
    for (int ks = 0; ks < 2; ++ks) {
      const int kk2 = (ks * 32 + lhi * 8) * 2;
      bf16x8 af[2], bfr[8];
#pragma unroll
      for (int i = 0; i < 2; ++i) {
        int row = w * 32 + i * 16 + l15;
        af[i] = *(const bf16x8*)((const char*)As + row * 128 + (kk2 ^ ((row & 7) << 4)));
      }
#pragma unroll
      for (int j = 0; j < 8; ++j) {
        int row = j * 16 + l15;
        bfr[j] = *(const bf16x8*)((const char*)Bs + row * 128 + (kk2 ^ ((row & 7) << 4)));
      }
#pragma unroll
      for (int i = 0; i < 2; ++i)
#pragma unroll
        for (int j = 0; j < 8; ++j) acc[i][j] = MFMA16(af[i], bfr[j], acc[i][j]);
    }
    __syncthreads();
  }

  const int h = nbase >> 7;
  if constexpr (EPI == 3) {
    float* out = (float*)outp;
#pragma unroll
    for (int i = 0; i < 2; ++i)
#pragma unroll
      for (int r = 0; r < 4; ++r) {
        size_t m = (size_t)(mbase + w * 32 + i * 16 + lhi * 4 + r);
#pragma unroll
        for (int j = 0; j < 8; ++j) out[m * 4096 + nbase + j * 16 + l15] = acc[i][j][r];
      }
  } else {
    u16* qo = (u16*)outp;
#pragma unroll
    for (int i = 0; i < 2; ++i)
#pragma unroll
      for (int r = 0; r < 4; ++r) {
        int m = mbase + w * 32 + i * 16 + lhi * 4 + r;
        int b = m >> 11, s = m & 2047;
        const float* ct = cost + (size_t)s * 64;
        const float* st = sint + (size_t)s * 64;
        size_t base = ((size_t)(b * 32 + h) * 2048 + s) * 128;
#pragma unroll
        for (int j = 0; j < 4; ++j) {
          int d = j * 16 + l15;
          float c = ct[d], sn = st[d];
          float x1 = acc[i][j][r], x2 = acc[i][j + 4][r];
          qo[base + d] = f2b(x1 * c - x2 * sn);
          qo[base + d + 64] = f2b(x2 * c + x1 * sn);
        }
      }
  }
}

__global__ __launch_bounds__(256) void k_gemmv(const float* __restrict__ hsf,
                                               const float* __restrict__ Wv,
                                               u16* __restrict__ vt) {
  __shared__ u16 AsHi[128 * 64];
  __shared__ u16 AsLo[128 * 64];
  __shared__ u16 BsHi[128 * 64];
  __shared__ u16 BsLo[128 * 64];
  const int tid = threadIdx.x;
  const int w = tid >> 6, lane = tid & 63;
  const int l15 = lane & 15, lhi = lane >> 4;
  const int mbase = blockIdx.y * 128, nbase = blockIdx.x * 128;
  f32x4 acc[2][8];
#pragma unroll
  for (int i = 0; i < 2; ++i)
#pragma unroll
    for (int j = 0; j < 8; ++j) acc[i][j] = (f32x4){0.f, 0.f, 0.f, 0.f};

  const int srow = tid >> 1, sk = (tid & 1) * 32;
  const float* asrc = hsf + (size_t)(mbase + srow) * 4096 + sk;
  const float* bsrc = Wv + (size_t)(nbase + srow) * 4096 + sk;

  for (int kt = 0; kt < 64; ++kt) {
    const int k0 = kt * 64;
    float4 av[8], bv[8];
#pragma unroll
    for (int c = 0; c < 8; ++c) {
      av[c] = *(const float4*)(asrc + k0 + c * 4);
      bv[c] = *(const float4*)(bsrc + k0 + c * 4);
    }
#pragma unroll
    for (int c = 0; c < 4; ++c) {
      u16 h0, l0, h1, l1;
      float fa[8] = {av[2 * c].x, av[2 * c].y, av[2 * c].z, av[2 * c].w,
                     av[2 * c + 1].x, av[2 * c + 1].y, av[2 * c + 1].z, av[2 * c + 1].w};
      float fb[8] = {bv[2 * c].x, bv[2 * c].y, bv[2 * c].z, bv[2 * c].w,
                     bv[2 * c + 1].x, bv[2 * c + 1].y, bv[2 * c + 1].z, bv[2 * c + 1].w};
      u32 ph[4], pl[4], qh[4], ql[4];
#pragma unroll
      for (int t = 0; t < 4; ++t) {
        split2(fa[2 * t], h0, l0);
        split2(fa[2 * t + 1], h1, l1);
        ph[t] = (u32)h0 | ((u32)h1 << 16);
        pl[t] = (u32)l0 | ((u32)l1 << 16);
        split2(fb[2 * t], h0, l0);
        split2(fb[2 * t + 1], h1, l1);
        qh[t] = (u32)h0 | ((u32)h1 << 16);
        ql[t] = (u32)l0 | ((u32)l1 << 16);
      }
      int byte = srow * 128 + (((sk + c * 8) * 2) ^ ((srow & 7) << 4));
      *(uint4*)((char*)AsHi + byte) = make_uint4(ph[0], ph[1], ph[2], ph[3]);
      *(uint4*)((char*)AsLo + byte) = make_uint4(pl[0], pl[1], pl[2], pl[3]);
      *(uint4*)((char*)BsHi + byte) = make_uint4(qh[0], qh[1], qh[2], qh[3]);
      *(uint4*)((char*)BsLo + byte) = make_uint4(ql[0], ql[1], ql[2], ql[3]);
    }
    __syncthreads();
#pragma unroll
    for (int ks = 0; ks < 2; ++ks) {
      const int kk2 = (ks * 32 + lhi * 8) * 2;
      bf16x8 afh[2], afl[2];
#pragma unroll
      for (int i = 0; i < 2; ++i) {
        int row = w * 32 + i * 16 + l15;
        int off = row * 128 + (kk2 ^ ((row & 7) << 4));
        afh[i] = *(const bf16x8*)((const char*)AsHi + off);
        afl[i] = *(const bf16x8*)((const char*)AsLo + off);
      }
#pragma unroll
      for (int j = 0; j < 8; ++j) {
        int row = j * 16 + l15;
        int off = row * 128 + (kk2 ^ ((row & 7) << 4));
        bf16x8 bh = *(const bf16x8*)((const char*)BsHi + off);
        bf16x8 bl = *(const bf16x8*)((const char*)BsLo + off);
#pragma unroll
        for (int i = 0; i < 2; ++i) {
          acc[i][j] = MFMA16(afh[i], bh, acc[i][j]);
          acc[i][j] = MFMA16(afh[i], bl, acc[i][j]);
          acc[i][j] = MFMA16(afl[i], bh, acc[i][j]);
        }
      }
    }
    __syncthreads();
  }

  const int h = nbase >> 7;
  float pam[8];
#pragma unroll
  for (int j = 0; j < 8; ++j) {
    float a = 0.f;
#pragma unroll
    for (int i = 0; i < 2; ++i)
#pragma unroll
      for (int r = 0; r < 4; ++r) a = fmaxf(a, fabsf(acc[i][j][r]));
    a = fmaxf(a, __shfl_xor(a, 16));
    a = fmaxf(a, __shfl_xor(a, 32));
    pam[j] = a;
  }
  float* red = (float*)BsHi;
  if (lhi == 0) {
#pragma unroll
    for (int j = 0; j < 8; ++j) red[w * 128 + j * 16 + l15] = pam[j];
  }
  __syncthreads();
#pragma unroll
  for (int j = 0; j < 8; ++j) {
    float amax = fmaxf(fmaxf(red[0 * 128 + j * 16 + l15], red[1 * 128 + j * 16 + l15]),
                       fmaxf(red[2 * 128 + j * 16 + l15], red[3 * 128 + j * 16 + l15]));
    float scale = 1.f, rs = 1.f;
    if (amax > 0.f) {
      int e;
      float mant = frexpf(amax, &e);
      int c = (mant == 0.5f) ? (e - 1) : e;
      scale = ldexpf(1.f, c - 3);
      rs = ldexpf(1.f, 3 - c);
    }
#pragma unroll
    for (int i = 0; i < 2; ++i) {
      int m0 = mbase + w * 32 + i * 16 + lhi * 4;
      int b = m0 >> 11, s0 = m0 & 2047;
      int d = j * 16 + l15;
      uint2 pk;
      float v0 = quant1(acc[i][j][0], scale, rs);
      float v1 = quant1(acc[i][j][1], scale, rs);
      float v2 = quant1(acc[i][j][2], scale, rs);
      float v3 = quant1(acc[i][j][3], scale, rs);
      pk.x = (u32)f2b(v0) | ((u32)f2b(v1) << 16);
      pk.y = (u32)f2b(v2) | ((u32)f2b(v3) << 16);
      *(uint2*)(vt + ((size_t)(b * 32 + h) * 128 + d) * 2048 + s0) = pk;
    }
  }
}

// ---------------- R12 flash attention (causal): QB=128 (8 waves), KB=64,
// swapped QK^T (lane-local softmax rows) + T13 defer-max (RESCALE_THRESHOLD=8):
// skip alpha/exp/shuffles/oacc-rescale when __all(tm <= mr + 8).
__global__ __launch_bounds__(512, 4) void k_attn(const u16* __restrict__ qg,
                                                 const u16* __restrict__ kg,
                                                 const u16* __restrict__ vtg,
                                                 u16* __restrict__ ao) {
  __shared__ u16 Ks[2][64 * 128];  // 32KB: [kk][d], 256B rows, swizzled by ((row&15)<<4)
  __shared__ u16 Vs[2][128 * 64];  // 32KB: [d][s], 128B rows, swizzled by ((row&7)<<4)
  __shared__ u16 Ps[8 * 16 * 64];  // 16KB: per-wave P [16 q][64 k], byte ^= ((q&7)<<4)
  const int qt = 15 - blockIdx.y;  // longest blocks dispatch first
  const int bh = blockIdx.x;
  const int tid = threadIdx.x, w = tid >> 6, lane = tid & 63;
  const int l15 = lane & 15, lhi = lane >> 4;
  const size_t bhoff = (size_t)bh * (2048 * 128);
  const float SC = 0.08838834764831845f;  // 1/sqrt(128)

  bf16x8 qf[4];
  {
    const int qrow = qt * 128 + w * 16 + l15;
    const u16* qp = qg + bhoff + (size_t)qrow * 128 + lhi * 8;
#pragma unroll
    for (int ks = 0; ks < 4; ++ks) qf[ks] = *(const bf16x8*)(qp + ks * 32);
  }
  f32x4 oacc[8];
#pragma unroll
  for (int dt = 0; dt < 8; ++dt) oacc[dt] = (f32x4){0.f, 0.f, 0.f, 0.f};
  float mr = -1e30f, lr = 0.f;  // online-softmax state for q = w*16 + l15 (lane-local)

  auto stage = [&](int buf, int kbase) {
#pragma unroll
    for (int i = 0; i < 2; ++i) {
      int idx = i * 512 + tid;
      int row = idx >> 4;
      int inb = ((idx & 15) << 4) ^ ((row & 15) << 4);
      gload16(kg + bhoff + (size_t)(kbase + row) * 128 + (inb >> 1), (char*)Ks[buf] + idx * 16);
    }
#pragma unroll
    for (int i = 0; i < 2; ++i) {
      int idx = i * 512 + tid;
      int row = idx >> 3;
      int inb = ((idx & 7) << 4) ^ ((row & 7) << 4);
      gload16(vtg + bhoff + (size_t)row * 2048 + kbase + (inb >> 1), (char*)Vs[buf] + idx * 16);
    }
  };

  const int nt = 2 * qt + 2;
  stage(0, 0);

  for (int kt = 0; kt < nt; ++kt) {
    const int cur = kt & 1;
    if (kt < nt - 1) {
      stage(cur ^ 1, (kt + 1) * 64);
      asm volatile("s_waitcnt vmcnt(4)" ::: "memory");
    } else {
      asm volatile("s_waitcnt vmcnt(0)" ::: "memory");
    }
    __builtin_amdgcn_s_barrier();

    // swapped QK^T: mfma(K, Q) -> C[m=k][n=q]; lane: q = l15, k = j*16 + lhi*4 + r
    f32x4 sc4[4];
#pragma unroll
    for (int j = 0; j < 4; ++j) sc4[j] = (f32x4){0.f, 0.f, 0.f, 0.f};
    __builtin_amdgcn_s_setprio(1);
#pragma unroll
    for (int ks = 0; ks < 4; ++ks) {
      const int db = (ks * 32 + lhi * 8) * 2;
#pragma unroll
      for (int j = 0; j < 4; ++j) {
        int kr = j * 16 + l15;
        bf16x8 bfr = *(const bf16x8*)((const char*)Ks[cur] + kr * 256 + (db ^ ((kr & 15) << 4)));
        sc4[j] = MFMA16(bfr, qf[ks], sc4[j]);
      }
    }
    __builtin_amdgcn_s_setprio(0);
    float p[4][4];
    const int kbase = kt * 64;
    const bool tail = (kt >= 2 * qt);
    const int qrow = qt * 128 + w * 16 + l15;
#pragma unroll
    for (int j = 0; j < 4; ++j)
#pragma unroll
      for (int r = 0; r < 4; ++r) {
        float s = sc4[j][r] * SC;
        if (tail && (kbase + j * 16 + lhi * 4 + r > qrow)) s = -1e9f;
        p[j][r] = s;
      }
    // lane-local softmax for q = l15's row + 2-shuffle cross-group reduce
    float tm = -1e30f;
#pragma unroll
    for (int j = 0; j < 4; ++j)
#pragma unroll
      for (int r = 0; r < 4; ++r) tm = fmaxf(tm, p[j][r]);
    tm = fmaxf(tm, __shfl_xor(tm, 16));
    tm = fmaxf(tm, __shfl_xor(tm, 32));
    // T13 defer-max: skip rescale when all rows' max growth <= 8 (P bounded by e^8)
    if (!__all(tm <= mr + 8.f)) {
      float mn = fmaxf(mr, tm);
      float alpha = __expf(mr - mn);
      mr = mn;
      lr *= alpha;
      float aq[4];
#pragma unroll
      for (int r = 0; r < 4; ++r) aq[r] = __shfl(alpha, (lane & 48) | (lhi * 4 + r));
#pragma unroll
      for (int dt = 0; dt < 8; ++dt) {
        f32x4 t = oacc[dt];
        t[0] *= aq[0]; t[1] *= aq[1]; t[2] *= aq[2]; t[3] *= aq[3];
        oacc[dt] = t;
      }
    }
    float rsum = 0.f;
#pragma unroll
    for (int j = 0; j < 4; ++j)
#pragma unroll
      for (int r = 0; r < 4; ++r) {
        float e = __expf(p[j][r] - mr);
        p[j][r] = e;
        rsum += e;
      }
    rsum += __shfl_xor(rsum, 16);
    rsum += __shfl_xor(rsum, 32);
    lr += rsum;
    // P -> per-wave LDS [16 q][64 k]: per j, 4 consecutive k -> one ds_write_b64
#pragma unroll
    for (int j = 0; j < 4; ++j) {
      u32 lo = (u32)f2b(p[j][0]) | ((u32)f2b(p[j][1]) << 16);
      u32 hi = (u32)f2b(p[j][2]) | ((u32)f2b(p[j][3]) << 16);
      int byte = w * 2048 + l15 * 128 + (((j * 16 + lhi * 4) * 2) ^ ((l15 & 7) << 4));
      *(uint2*)((char*)Ps + byte) = make_uint2(lo, hi);
    }
    __builtin_amdgcn_s_setprio(1);
#pragma unroll
    for (int ks2 = 0; ks2 < 2; ++ks2) {
      const int sb = ks2 * 32 + lhi * 8;
      bf16x8 pa = *(const bf16x8*)((const char*)Ps + w * 2048 + l15 * 128 +
                                   ((sb * 2) ^ ((l15 & 7) << 4)));
#pragma unroll
      for (int dt = 0; dt < 8; ++dt) {
        int d = dt * 16 + l15;
        bf16x8 vb = *(const bf16x8*)((const char*)Vs[cur] + d * 128 + ((sb * 2) ^ ((d & 7) << 4)));
        oacc[dt] = MFMA16(pa, vb, oacc[dt]);
      }
    }
    __builtin_amdgcn_s_setprio(0);
    asm volatile("s_waitcnt lgkmcnt(0)" ::: "memory");
    __builtin_amdgcn_s_barrier();
  }

  const int b = bh >> 5, h = bh & 31;
  float linv = 1.f / lr;  // for q = l15
  float inv[4];
#pragma unroll
  for (int r = 0; r < 4; ++r) inv[r] = __shfl(linv, (lane & 48) | (lhi * 4 + r));
#pragma unroll
  for (int dt = 0; dt < 8; ++dt)
#pragma unroll
    for (int r = 0; r < 4; ++r) {
      int s = qt * 128 + w * 16 + lhi * 4 + r;
      ao[((size_t)(b * 2048 + s)) * 4096 + h * 128 + dt * 16 + l15] = f2b(oacc[dt][r] * inv[r]);
    }
}

extern "C" void kernel_launch(void* const* d_in, const int* in_sizes, int n_in,
                              void* d_out, int out_size, void* d_ws, size_t ws_size,
                              hipStream_t stream) {
  (void)in_sizes; (void)n_in; (void)out_size;
  const float* hs = (const float*)d_in[0];
  const int* pid = (const int*)d_in[1];
  const float* Wq = (const float*)d_in[2];
  const float* Wk = (const float*)d_in[3];
  const float* Wv = (const float*)d_in[4];
  const float* Wo = (const float*)d_in[5];
  float* out = (float*)d_out;
  char* ws = (char*)d_ws;

  const size_t BUF = 33554432;  // one 4096x4096 bf16 buffer
  const size_t NEED = 7 * BUF + 2 * 524288;

  if (ws_size >= NEED) {
    u16* hsb  = (u16*)(ws + 0 * BUF);          // hs hi
    u16* hslo = (u16*)(ws + 1 * BUF);          // hs lo; later aob
    u16* qb   = (u16*)(ws + 2 * BUF);
    u16* kb   = (u16*)(ws + 3 * BUF);
    u16* vtb  = (u16*)(ws + 4 * BUF);
    u16* wbuf = (u16*)(ws + 5 * BUF);          // Wq_b -> Wk_b -> Wv_hi -> Wo_b (sequential)
    u16* wvlo = (u16*)(ws + 6 * BUF);
    float* cost = (float*)(ws + 7 * BUF);
    float* sint = (float*)(ws + 7 * BUF + 524288);
    u16* aob = hslo;

    k_splt<<<16384, 256, 0, stream>>>(hs, hsb, hslo);
    k_rope_tab<<<512, 256, 0, stream>>>(pid, cost, sint);
    k_cvt<<<16384, 256, 0, stream>>>(Wq, wbuf);
    k_gemm8<0><<<256, 512, 0, stream>>>(hsb, wbuf, (void*)qb, cost, sint);
    k_cvt<<<16384, 256, 0, stream>>>(Wk, wbuf);
    k_gemm8<1><<<256, 512, 0, stream>>>(hsb, wbuf, (void*)kb, cost, sint);
    k_splt<<<16384, 256, 0, stream>>>(Wv, wbuf, wvlo);
    k_gemmv4<<<256, 512, 0, stream>>>(hsb, hslo, wbuf, wvlo, vtb);
    k_attn<<<dim3(64, 16), 512, 0, stream>>>(qb, kb, vtb, aob);
    k_cvt<<<16384, 256, 0, stream>>>(Wo, wbuf);
    k_gemm8<3><<<256, 512, 0, stream>>>(aob, wbuf, (void*)out, nullptr, nullptr);
  } else {
    u16* hsb = (u16*)(ws + 0);
    u16* qb  = (u16*)(ws + 33554432);
    u16* kb  = (u16*)(ws + 67108864);
    u16* vtb = (u16*)(ws + 100663296);
    float* cost = (float*)(ws + 134217728);
    float* sint = (float*)(ws + 134742016);
    u16* aob = hsb;

    k_cvt<<<16384, 256, 0, stream>>>(hs, hsb);
    k_rope_tab<<<512, 256, 0, stream>>>(pid, cost, sint);
    k_gemm<0><<<dim3(32, 32), 256, 0, stream>>>(hsb, Wq, (void*)qb, cost, sint);
    k_gemm<1><<<dim3(32, 32), 256, 0, stream>>>(hsb, Wk, (void*)kb, cost, sint);
    k_gemmv<<<dim3(32, 32), 256, 0, stream>>>(hs, Wv, vtb);
    k_attn<<<dim3(64, 16), 512, 0, stream>>>(qb, kb, vtb, aob);
    k_gemm<3><<<dim3(32, 32), 256, 0, stream>>>(aob, Wo, (void*)out, nullptr, nullptr);
  }
}